// Round 9
// baseline (561.600 us; speedup 1.0000x reference)
//
#include <hip/hip_runtime.h>
#include <cstdint>
#include <cstddef>

// ---------------------------------------------------------------------------
// TransformerLayer: hidden,k,v = f(x, qw,qb, kw,kb, vw,vb, w1,b1, w2,b2)
// S=4096, D_MODEL=2048, D_INT=512.  bf16 MFMA GEMMs, fp32 accumulate.
// Round 9: all big GEMMs through the m201-class phase-interleaved 256^2
// kernel (per-wave 128x64, reads/MFMA=0.375).  N=2048 GEMMs run grid 128
// (half machine, 1 blk/CU) -- measured trade vs the 600-TF coarse kernel.
// ---------------------------------------------------------------------------

typedef __attribute__((ext_vector_type(8))) short short8;   // 8 x bf16 bits
typedef __attribute__((ext_vector_type(4))) float f32x4;    // MFMA accum

typedef __attribute__((address_space(3))) void lds_void;
typedef __attribute__((address_space(1))) void g_void;

#define SEQ    4096
#define DMODEL 2048
#define DINT   512

#define MEMF() asm volatile("" ::: "memory")
#define BARRIER() do { MEMF(); __builtin_amdgcn_s_barrier(); MEMF(); } while (0)
#define VMCNT6() asm volatile("s_waitcnt vmcnt(6)" ::: "memory")
#define VMCNT0() asm volatile("s_waitcnt vmcnt(0)" ::: "memory")

// fp32 -> bf16 bits, round-to-nearest-even
__device__ __forceinline__ unsigned short f2bf(float f) {
  union { float f; unsigned int u; } a;
  a.f = f;
  unsigned int u = a.u;
  u += 0x7fffu + ((u >> 16) & 1u);
  return (unsigned short)(u >> 16);
}

// ---------------------------------------------------------------------------
// cast: fp32 -> bf16 (4 elems / thread)
// ---------------------------------------------------------------------------
__global__ __launch_bounds__(256) void cast_bf16_kernel(
    const float* __restrict__ in, unsigned short* __restrict__ out, int n4) {
  int i = blockIdx.x * 256 + threadIdx.x;
  if (i >= n4) return;
  float4 v = ((const float4*)in)[i];
  ushort4 o;
  o.x = f2bf(v.x); o.y = f2bf(v.y); o.z = f2bf(v.z); o.w = f2bf(v.w);
  ((ushort4*)out)[i] = o;
}

// ---------------------------------------------------------------------------
// bf16 transpose: out[C][R] = in[R][C].  64x64 LDS tile.
// ---------------------------------------------------------------------------
__global__ __launch_bounds__(256) void transpose_bf16_kernel(
    const unsigned short* __restrict__ in, unsigned short* __restrict__ out,
    int R, int C) {
  __shared__ unsigned short tile[64][65];
  const int tx = threadIdx.x & 63;
  const int ty = threadIdx.x >> 6;
  const int r0 = blockIdx.x * 64;
  const int c0 = blockIdx.y * 64;
#pragma unroll
  for (int i = 0; i < 64; i += 4)
    tile[ty + i][tx] = in[(size_t)(r0 + ty + i) * C + c0 + tx];
  __syncthreads();
#pragma unroll
  for (int i = 0; i < 64; i += 4)
    out[(size_t)(c0 + ty + i) * R + r0 + tx] = tile[tx][ty + i];
}

// ---------------------------------------------------------------------------
// 2-phase 128^2 GEMM, kept for the QK fused GEMM (N=1024, grid 32x8 = 256).
// ---------------------------------------------------------------------------
#define BM 128
#define BN 128
#define BK 64

__global__ __launch_bounds__(256)
void gemm_bt_kernel(const unsigned short* __restrict__ A,
                    const unsigned short* __restrict__ B,
                    int M, int N, int K, int split,
                    const float* __restrict__ biasA,
                    const float* __restrict__ biasB,
                    const float* __restrict__ resid,
                    float scale, int relu,
                    float* __restrict__ outFA,
                    unsigned short* __restrict__ outBA,
                    float* __restrict__ outFB,
                    unsigned short* __restrict__ outBB)
{
  __shared__ __align__(16) unsigned short As[2][BM][BK];
  __shared__ __align__(16) unsigned short Bs[2][BN][BK];

  const int tid  = threadIdx.x;
  const int lane = tid & 63;
  const int wave = tid >> 6;
  const int wr   = wave >> 1;
  const int wc   = wave & 1;
  const int brow = blockIdx.x * BM;
  const int bcol = blockIdx.y * BN;
  const int lr   = lane & 15;
  const int kg   = lane >> 4;

  const int srow  = tid >> 3;
  const int scol  = (tid & 7) * 8;
  const int wbase = wave * 8;
  const unsigned short* Ab = A + (size_t)(brow + srow) * K + scol;
  const unsigned short* Bb = B + (size_t)(bcol + srow) * K + scol;

  f32x4 acc[4][4];
#pragma unroll
  for (int i = 0; i < 4; i++)
#pragma unroll
    for (int j = 0; j < 4; j++) acc[i][j] = (f32x4){0.f, 0.f, 0.f, 0.f};

  auto stage = [&](int d, int k0) {
#pragma unroll
    for (int j = 0; j < 4; ++j) {
      __builtin_amdgcn_global_load_lds((const g_void*)(Ab + (size_t)(j * 32) * K + k0),
                                       (lds_void*)&As[d][j * 32 + wbase][0], 16, 0, 0);
      __builtin_amdgcn_global_load_lds((const g_void*)(Bb + (size_t)(j * 32) * K + k0),
                                       (lds_void*)&Bs[d][j * 32 + wbase][0], 16, 0, 0);
    }
  };

  auto compute = [&](int d) {
    short8 aF[4][2], bF[4][2];
#pragma unroll
    for (int mi = 0; mi < 4; ++mi)
#pragma unroll
      for (int ks = 0; ks < 2; ++ks)
        aF[mi][ks] = *(const short8*)&As[d][wr * 64 + mi * 16 + lr][ks * 32 + kg * 8];
#pragma unroll
    for (int ni = 0; ni < 4; ++ni)
#pragma unroll
      for (int ks = 0; ks < 2; ++ks)
        bF[ni][ks] = *(const short8*)&Bs[d][wc * 64 + ni * 16 + lr][ks * 32 + kg * 8];
#pragma unroll
    for (int ks = 0; ks < 2; ++ks)
#pragma unroll
      for (int mi = 0; mi < 4; ++mi)
#pragma unroll
        for (int ni = 0; ni < 4; ++ni)
          acc[mi][ni] = __builtin_amdgcn_mfma_f32_16x16x32_bf16(
              aF[mi][ks], bF[ni][ks], acc[mi][ni], 0, 0, 0);
  };

  stage(0, 0);
  __syncthreads();
  int c = 0;
  const int NT = K >> 6;
  for (int t = 0; t < NT; ++t) {
    if (t + 1 < NT) stage(c ^ 1, (t + 1) << 6);
    compute(c);
    __syncthreads();
    c ^= 1;
  }

  const int wB = N - split;
#pragma unroll
  for (int mi = 0; mi < 4; mi++) {
#pragma unroll
    for (int ni = 0; ni < 4; ni++) {
#pragma unroll
      for (int r = 0; r < 4; r++) {
        const int row = brow + wr * 64 + mi * 16 + kg * 4 + r;
        const int col = bcol + wc * 64 + ni * 16 + lr;
        float v = acc[mi][ni][r] * scale;
        if (col < split) {
          if (biasA) v += biasA[col];
          if (resid) v += resid[(size_t)row * N + col];
          if (relu)  v = fmaxf(v, 0.0f);
          if (outFA) outFA[(size_t)row * split + col] = v;
          if (outBA) outBA[(size_t)row * split + col] = f2bf(v);
        } else {
          const int c2 = col - split;
          if (biasB) v += biasB[c2];
          if (outFB) outFB[(size_t)row * wB + c2] = v;
          if (outBB) outBB[(size_t)row * wB + c2] = f2bf(v);
        }
      }
    }
  }
}

// ---------------------------------------------------------------------------
// 256^2 phase-interleaved GEMM (m201-structure port).  1-D grid = 16*nty
// blocks over a (16 x nty) tile map, bijective XCD-rect swizzle.
// 8 waves 2Mx4N, per-wave 128x64.  LDS [op][dbuf][half][128][64] = 128 KiB.
// 4 phases per K-tile: {ds_read frags | stage quarters | bar | 16 MFMA
// (setprio) | bar}; counted vmcnt(6) once per tile (never 0).
// ---------------------------------------------------------------------------
__global__ __launch_bounds__(512, 2)
void gemm256_kernel(const unsigned short* __restrict__ A,
                    const unsigned short* __restrict__ B,
                    int M, int N, int K, int nty,
                    const float* __restrict__ bias,
                    const float* __restrict__ resid,
                    float scale, int relu,
                    float* __restrict__ outF,
                    unsigned short* __restrict__ outB)
{
  __shared__ __align__(16) unsigned short lds[2][2][2][128][64];  // 128 KiB

  const int tid  = threadIdx.x;
  const int lane = tid & 63;
  const int wave = tid >> 6;     // 0..7
  const int wm   = wave >> 2;    // 0..1  (128-row half)
  const int wn   = wave & 3;     // 0..3  (64-col strip)
  const int lr   = lane & 15;
  const int kg   = lane >> 4;

  // bijective XCD-rect swizzle over the (16 x nty) tile map
  int tx, ty;
  {
    const int f = blockIdx.x;
    const int xcd = f & 7, idx = f >> 3;
    if (nty == 16) {        // 256 blocks: each XCD an 8x4 rect
      tx = ((xcd >> 2) << 3) + (idx & 7);
      ty = ((xcd & 3) << 2) + (idx >> 3);
    } else if (nty == 8) {  // 128 blocks: each XCD a 4x4 rect
      tx = ((xcd >> 1) << 2) + (idx & 3);
      ty = ((xcd & 1) << 2) + (idx >> 2);
    } else {                // nty == 4: 64 blocks: each XCD a 2x4 rect
      tx = (xcd << 1) + (idx & 1);
      ty = idx >> 1;
    }
  }
  const int brow = tx * 256;
  const int bcol = ty * 256;

  const int srow = tid >> 3;                              // 0..63
  const int ssw  = ((tid & 7) * 8) ^ ((srow & 7) << 3);   // pre-swizzled k
  const unsigned short* Asrc = A + (size_t)(brow + srow) * K + ssw;
  const unsigned short* Bsrc = B + (size_t)(bcol + srow) * K + ssw;

  char* lbase = (char*)&lds[0][0][0][0][0];
  const int woff = wave * 1024;

  f32x4 acc[8][4];
#pragma unroll
  for (int i = 0; i < 8; ++i)
#pragma unroll
    for (int j = 0; j < 4; ++j) acc[i][j] = (f32x4){0.f, 0.f, 0.f, 0.f};

  const int NT = K >> 6;

  auto SA = [&](int d, int h, int q, int tl) {
    __builtin_amdgcn_global_load_lds(
        (const g_void*)(Asrc + (size_t)(h * 128 + q * 64) * K + tl * 64),
        (lds_void*)(lbase + d * 32768 + h * 16384 + q * 8192 + woff), 16, 0, 0);
  };
  auto SB = [&](int d, int h, int q, int tl) {
    __builtin_amdgcn_global_load_lds(
        (const g_void*)(Bsrc + (size_t)(h * 128 + q * 64) * K + tl * 64),
        (lds_void*)(lbase + 65536 + d * 32768 + h * 16384 + q * 8192 + woff), 16, 0, 0);
  };

  auto LDA = [&](short8* a, int d, int mh, int ks) {
    const char* reg = lbase + d * 32768 + wm * 16384;
    const int ke = (ks * 32 + kg * 8) ^ ((lr & 7) << 3);
#pragma unroll
    for (int i = 0; i < 4; ++i) {
      const int row = (mh * 4 + i) * 16 + lr;
      a[i] = *(const short8*)(reg + row * 128 + ke * 2);
    }
  };
  auto LDB = [&](short8* b, int d, int ks) {
    const char* reg = lbase + 65536 + d * 32768 + (wn >> 1) * 16384;
    const int ke = (ks * 32 + kg * 8) ^ ((lr & 7) << 3);
#pragma unroll
    for (int n = 0; n < 4; ++n) {
      const int row = (wn & 1) * 64 + n * 16 + lr;
      b[n] = *(const short8*)(reg + row * 128 + ke * 2);
    }
  };

  auto MM = [&](int mh, short8* a, short8* b) {
    __builtin_amdgcn_s_setprio(1);
#pragma unroll
    for (int i = 0; i < 4; ++i)
#pragma unroll
      for (int n = 0; n < 4; ++n)
        acc[mh * 4 + i][n] = __builtin_amdgcn_mfma_f32_16x16x32_bf16(
            a[i], b[n], acc[mh * 4 + i][n], 0, 0, 0);
    __builtin_amdgcn_s_setprio(0);
  };

  // prologue: tile 0 full; tile 1 in steady p2/p3 issue order
  SA(0, 0, 0, 0); SA(0, 0, 1, 0); SA(0, 1, 0, 0); SA(0, 1, 1, 0);
  SB(0, 0, 0, 0); SB(0, 0, 1, 0); SB(0, 1, 0, 0); SB(0, 1, 1, 0);
  SB(1, 0, 0, 1); SB(1, 0, 1, 1); SA(1, 0, 0, 1);
  SB(1, 1, 0, 1); SB(1, 1, 1, 1); SA(1, 1, 0, 1);
  VMCNT6();
  BARRIER();

  short8 aT[4], bF0[4], bF1[4];
  for (int t = 0; t < NT; ++t) {
    const int buf = t & 1, nb = buf ^ 1;
    const int t1 = (t + 1 < NT) ? t + 1 : NT - 1;
    const int t2 = (t + 2 < NT) ? t + 2 : NT - 1;

    // p0: frags (mh0,ks0)+B(ks0); stage A(t+1) q1 quarters -> buf^1
    LDA(aT, buf, 0, 0); LDB(bF0, buf, 0);
    SA(nb, 0, 1, t1); SA(nb, 1, 1, t1);
    BARRIER(); MM(0, aT, bF0); BARRIER();

    // p1: frags (mh0,ks1)+B(ks1)
    LDA(aT, buf, 0, 1); LDB(bF1, buf, 1);
    BARRIER(); MM(0, aT, bF1); BARRIER();

    // p2: frags (mh1,ks0); stage B(t+2).h0 + A(t+2).h0q0 -> live buf
    LDA(aT, buf, 1, 0);
    SB(buf, 0, 0, t2); SB(buf, 0, 1, t2); SA(buf, 0, 0, t2);
    BARRIER(); MM(1, aT, bF0); BARRIER();

    // p3: frags (mh1,ks1); stage B(t+2).h1 + A(t+2).h1q0 -> live buf
    LDA(aT, buf, 1, 1);
    SB(buf, 1, 0, t2); SB(buf, 1, 1, t2); SA(buf, 1, 0, t2);
    BARRIER(); MM(1, aT, bF1);
    VMCNT6();
    BARRIER();
  }
  VMCNT0();

#pragma unroll
  for (int mi = 0; mi < 8; ++mi) {
#pragma unroll
    for (int ni = 0; ni < 4; ++ni) {
#pragma unroll
      for (int r = 0; r < 4; ++r) {
        const int row = brow + wm * 128 + mi * 16 + kg * 4 + r;
        const int col = bcol + wn * 64 + ni * 16 + lr;
        float v = acc[mi][ni][r] * scale;
        if (bias)  v += bias[col];
        if (resid) v += resid[(size_t)row * N + col];
        if (relu)  v = fmaxf(v, 0.0f);
        if (outF)  outF[(size_t)row * N + col] = v;
        if (outB)  outB[(size_t)row * N + col] = f2bf(v);
      }
    }
  }
}

// ---------------------------------------------------------------------------
// row softmax: one block per row of [SEQ, SEQ] fp32 scores -> bf16 probs
// ---------------------------------------------------------------------------
__global__ __launch_bounds__(256) void softmax_kernel(
    const float* __restrict__ Sc, unsigned short* __restrict__ P) {
  __shared__ float buf[SEQ];
  __shared__ float redm[4];
  __shared__ float reds[4];
  const int tid = threadIdx.x;
  const int row = blockIdx.x;
  const float* src = Sc + (size_t)row * SEQ;

  float lmax = -3.0e38f;
  for (int i = tid * 4; i < SEQ; i += 1024) {
    float4 v = *(const float4*)(src + i);
    buf[i] = v.x; buf[i + 1] = v.y; buf[i + 2] = v.z; buf[i + 3] = v.w;
    lmax = fmaxf(lmax, fmaxf(fmaxf(v.x, v.y), fmaxf(v.z, v.w)));
  }
#pragma unroll
  for (int off = 32; off > 0; off >>= 1)
    lmax = fmaxf(lmax, __shfl_xor(lmax, off, 64));
  if ((tid & 63) == 0) redm[tid >> 6] = lmax;
  __syncthreads();
  const float m = fmaxf(fmaxf(redm[0], redm[1]), fmaxf(redm[2], redm[3]));

  float lsum = 0.0f;
  for (int i = tid; i < SEQ; i += 256) {
    float e = __expf(buf[i] - m);
    buf[i] = e;
    lsum += e;
  }
#pragma unroll
  for (int off = 32; off > 0; off >>= 1)
    lsum += __shfl_xor(lsum, off, 64);
  if ((tid & 63) == 0) reds[tid >> 6] = lsum;
  __syncthreads();
  const float inv = 1.0f / (reds[0] + reds[1] + reds[2] + reds[3]);

  unsigned short* dst = P + (size_t)row * SEQ;
  for (int i = tid; i < SEQ; i += 256) dst[i] = f2bf(buf[i] * inv);
}

// ---------------------------------------------------------------------------
// launch
// ---------------------------------------------------------------------------
extern "C" void kernel_launch(void* const* d_in, const int* in_sizes, int n_in,
                              void* d_out, int out_size, void* d_ws, size_t ws_size,
                              hipStream_t stream) {
  const float* x  = (const float*)d_in[0];
  const float* qw = (const float*)d_in[1];
  const float* qb = (const float*)d_in[2];
  const float* kw = (const float*)d_in[3];
  const float* kb = (const float*)d_in[4];
  const float* vw = (const float*)d_in[5];
  const float* vb = (const float*)d_in[6];
  const float* w1 = (const float*)d_in[7];
  const float* b1 = (const float*)d_in[8];
  const float* w2 = (const float*)d_in[9];
  const float* b2 = (const float*)d_in[10];
  float* out = (float*)d_out;   // [hidden(8388608) | k(2097152) | v(8388608)]
  char* ws = (char*)d_ws;

  const size_t MB = 1048576;
  unsigned short* Xb   = (unsigned short*)(ws + 0 * MB);
  unsigned short* VWb  = (unsigned short*)(ws + 16 * MB);
  unsigned short* QKWb = (unsigned short*)(ws + 24 * MB);
  unsigned short* Pb   = (unsigned short*)(ws + 0 * MB);     // overlays Xb/VWb/QKWb
  unsigned short* W1b  = (unsigned short*)(ws + 32 * MB);
  unsigned short* W2b  = (unsigned short*)(ws + 40 * MB);
  unsigned short* Qb   = (unsigned short*)(ws + 48 * MB);
  unsigned short* Kb   = (unsigned short*)(ws + 52 * MB);
  unsigned short* Vb   = (unsigned short*)(ws + 56 * MB);
  unsigned short* VTb  = (unsigned short*)(ws + 72 * MB);
  float*          Sc   = (float*)(ws + 88 * MB);
  float*          XR   = (float*)(ws + 88 * MB);             // overlays dead Sc
  unsigned short* X1b  = (unsigned short*)(ws + 120 * MB);   // overlays dead Sc
  unsigned short* XRb  = (unsigned short*)(ws + 136 * MB);   // overlays dead Sc

  // casts to bf16 (QKWb = [qw ; kw] rows concatenated)
  cast_bf16_kernel<<<8192, 256, 0, stream>>>(x,  Xb,  2097152);
  cast_bf16_kernel<<<1024, 256, 0, stream>>>(qw, QKWb, 262144);
  cast_bf16_kernel<<<1024, 256, 0, stream>>>(kw, QKWb + 512 * 2048, 262144);
  cast_bf16_kernel<<<4096, 256, 0, stream>>>(vw, VWb, 1048576);
  cast_bf16_kernel<<<4096, 256, 0, stream>>>(w1, W1b, 1048576);
  cast_bf16_kernel<<<4096, 256, 0, stream>>>(w2, W2b, 1048576);

  // q,k = x @ [qw;kw]^T + [qb;kb]   (fused, split epilogue; 2-phase kernel)
  gemm_bt_kernel<<<dim3(32, 8), dim3(256), 0, stream>>>(
      Xb, QKWb, SEQ, 1024, DMODEL, 512, qb, kb, nullptr, 1.0f, 0,
      nullptr, Qb, out + 8388608, Kb);
  // v = x @ vw^T + vb   -> fp32 (out) + bf16        [grid 128, 256^2 tiles]
  gemm256_kernel<<<128, dim3(512), 0, stream>>>(
      Xb, VWb, SEQ, DMODEL, DMODEL, 8, vb, nullptr, 1.0f, 0,
      out + 10485760, Vb);
  // VTb = Vb^T  ([2048][4096])
  transpose_bf16_kernel<<<dim3(64, 32), dim3(256), 0, stream>>>(Vb, VTb, SEQ, DMODEL);
  // scores = (q @ k^T) / sqrt(512)  -> fp32          [grid 256]
  gemm256_kernel<<<256, dim3(512), 0, stream>>>(
      Qb, Kb, SEQ, SEQ, DINT, 16, nullptr, nullptr,
      0.04419417382415922f, 0, Sc, nullptr);
  // P = softmax(scores)  -> bf16
  softmax_kernel<<<4096, dim3(256), 0, stream>>>(Sc, Pb);
  // x_residual = P @ V + x  -> fp32 + bf16           [grid 128]
  gemm256_kernel<<<128, dim3(512), 0, stream>>>(
      Pb, VTb, SEQ, DMODEL, SEQ, 8, nullptr, x, 1.0f, 0, XR, XRb);
  // x1 = relu(x_residual @ w1^T + b1)  -> bf16       [grid 128]
  gemm256_kernel<<<128, dim3(512), 0, stream>>>(
      XRb, W1b, SEQ, DMODEL, DMODEL, 8, b1, nullptr, 1.0f, 1, nullptr, X1b);
  // hidden = x1 @ w2^T + b2 + x_residual  -> fp32    [grid 128]
  gemm256_kernel<<<128, dim3(512), 0, stream>>>(
      X1b, W2b, SEQ, DMODEL, DMODEL, 8, b2, XR, 1.0f, 0, out, nullptr);
}

// Round 10
// 381.678 us; speedup vs baseline: 1.4714x; 1.4714x over previous
//
#include <hip/hip_runtime.h>
#include <cstdint>
#include <cstddef>

// ---------------------------------------------------------------------------
// TransformerLayer: hidden,k,v = f(x, qw,qb, kw,kb, vw,vb, w1,b1, w2,b2)
// S=4096, D_MODEL=2048, D_INT=512.  bf16 MFMA GEMMs, fp32 accumulate.
// Round 10: revert to r7-measured-best kernels; add (1) QKV mega-fusion
// (one 128^2 2-phase GEMM, N=3072, 768 blocks = 3 blk/CU) and (2)
// register-resident softmax (no LDS row buffer).
// ---------------------------------------------------------------------------

typedef __attribute__((ext_vector_type(8))) short short8;   // 8 x bf16 bits
typedef __attribute__((ext_vector_type(4))) float f32x4;    // MFMA accum

typedef __attribute__((address_space(3))) void lds_void;
typedef __attribute__((address_space(1))) void g_void;

#define SEQ    4096
#define DMODEL 2048
#define DINT   512

#define MEMF() asm volatile("" ::: "memory")
#define BARRIER() do { MEMF(); __builtin_amdgcn_s_barrier(); MEMF(); } while (0)
#define VMCNT6() asm volatile("s_waitcnt vmcnt(6)" ::: "memory")
#define VMCNT0() asm volatile("s_waitcnt vmcnt(0)" ::: "memory")
#define LGKM0()  asm volatile("s_waitcnt lgkmcnt(0)" ::: "memory")

// fp32 -> bf16 bits, round-to-nearest-even
__device__ __forceinline__ unsigned short f2bf(float f) {
  union { float f; unsigned int u; } a;
  a.f = f;
  unsigned int u = a.u;
  u += 0x7fffu + ((u >> 16) & 1u);
  return (unsigned short)(u >> 16);
}

// ---------------------------------------------------------------------------
// cast: fp32 -> bf16 (4 elems / thread)
// ---------------------------------------------------------------------------
__global__ __launch_bounds__(256) void cast_bf16_kernel(
    const float* __restrict__ in, unsigned short* __restrict__ out, int n4) {
  int i = blockIdx.x * 256 + threadIdx.x;
  if (i >= n4) return;
  float4 v = ((const float4*)in)[i];
  ushort4 o;
  o.x = f2bf(v.x); o.y = f2bf(v.y); o.z = f2bf(v.z); o.w = f2bf(v.w);
  ((ushort4*)out)[i] = o;
}

// ---------------------------------------------------------------------------
// bf16 transpose: out[C][R] = in[R][C].  64x64 LDS tile.
// ---------------------------------------------------------------------------
__global__ __launch_bounds__(256) void transpose_bf16_kernel(
    const unsigned short* __restrict__ in, unsigned short* __restrict__ out,
    int R, int C) {
  __shared__ unsigned short tile[64][65];
  const int tx = threadIdx.x & 63;
  const int ty = threadIdx.x >> 6;
  const int r0 = blockIdx.x * 64;
  const int c0 = blockIdx.y * 64;
#pragma unroll
  for (int i = 0; i < 64; i += 4)
    tile[ty + i][tx] = in[(size_t)(r0 + ty + i) * C + c0 + tx];
  __syncthreads();
#pragma unroll
  for (int i = 0; i < 64; i += 4)
    out[(size_t)(c0 + ty + i) * R + r0 + tx] = tile[tx][ty + i];
}

// ---------------------------------------------------------------------------
// Fused QKV GEMM: 2-phase 128^2, BK=64.  A=[4096,2048] bf16, W=[3072,2048]
// bf16 ([qw;kw;vw]).  Grid (32,24) = 768 blocks = 3 blk/CU (the measured
// high-occupancy regime for this structure, m102/m103).
// Epilogue segments (block-uniform: bcol%128, boundaries at 512/1024):
//   col <  512 : q -> Qb bf16                       (stride 512)
//   col < 1024 : k -> outK fp32 + Kb bf16           (stride 512)
//   else       : v -> outV fp32 + Vb bf16           (stride 2048)
// ---------------------------------------------------------------------------
#define BM 128
#define BN 128
#define BK 64

__global__ __launch_bounds__(256)
void gemm_qkv_kernel(const unsigned short* __restrict__ A,
                     const unsigned short* __restrict__ W,
                     int M, int N, int K,
                     const float* __restrict__ qb,
                     const float* __restrict__ kb,
                     const float* __restrict__ vb,
                     float* __restrict__ outK,
                     float* __restrict__ outV,
                     unsigned short* __restrict__ Qb,
                     unsigned short* __restrict__ Kb,
                     unsigned short* __restrict__ Vb)
{
  __shared__ __align__(16) unsigned short As[2][BM][BK];
  __shared__ __align__(16) unsigned short Bs[2][BN][BK];

  const int tid  = threadIdx.x;
  const int lane = tid & 63;
  const int wave = tid >> 6;
  const int wr   = wave >> 1;
  const int wc   = wave & 1;
  const int brow = blockIdx.x * BM;
  const int bcol = blockIdx.y * BN;
  const int lr   = lane & 15;
  const int kg   = lane >> 4;

  const int srow  = tid >> 3;
  const int scol  = (tid & 7) * 8;
  const int wbase = wave * 8;
  const unsigned short* Ab = A + (size_t)(brow + srow) * K + scol;
  const unsigned short* Bb = W + (size_t)(bcol + srow) * K + scol;

  f32x4 acc[4][4];
#pragma unroll
  for (int i = 0; i < 4; i++)
#pragma unroll
    for (int j = 0; j < 4; j++) acc[i][j] = (f32x4){0.f, 0.f, 0.f, 0.f};

  auto stage = [&](int d, int k0) {
#pragma unroll
    for (int j = 0; j < 4; ++j) {
      __builtin_amdgcn_global_load_lds((const g_void*)(Ab + (size_t)(j * 32) * K + k0),
                                       (lds_void*)&As[d][j * 32 + wbase][0], 16, 0, 0);
      __builtin_amdgcn_global_load_lds((const g_void*)(Bb + (size_t)(j * 32) * K + k0),
                                       (lds_void*)&Bs[d][j * 32 + wbase][0], 16, 0, 0);
    }
  };

  auto compute = [&](int d) {
    short8 aF[4][2], bF[4][2];
#pragma unroll
    for (int mi = 0; mi < 4; ++mi)
#pragma unroll
      for (int ks = 0; ks < 2; ++ks)
        aF[mi][ks] = *(const short8*)&As[d][wr * 64 + mi * 16 + lr][ks * 32 + kg * 8];
#pragma unroll
    for (int ni = 0; ni < 4; ++ni)
#pragma unroll
      for (int ks = 0; ks < 2; ++ks)
        bF[ni][ks] = *(const short8*)&Bs[d][wc * 64 + ni * 16 + lr][ks * 32 + kg * 8];
#pragma unroll
    for (int ks = 0; ks < 2; ++ks)
#pragma unroll
      for (int mi = 0; mi < 4; ++mi)
#pragma unroll
        for (int ni = 0; ni < 4; ++ni)
          acc[mi][ni] = __builtin_amdgcn_mfma_f32_16x16x32_bf16(
              aF[mi][ks], bF[ni][ks], acc[mi][ni], 0, 0, 0);
  };

  stage(0, 0);
  __syncthreads();
  int c = 0;
  const int NT = K >> 6;
  for (int t = 0; t < NT; ++t) {
    if (t + 1 < NT) stage(c ^ 1, (t + 1) << 6);
    compute(c);
    __syncthreads();
    c ^= 1;
  }

#pragma unroll
  for (int mi = 0; mi < 4; mi++) {
#pragma unroll
    for (int ni = 0; ni < 4; ni++) {
#pragma unroll
      for (int r = 0; r < 4; r++) {
        const int row = brow + wr * 64 + mi * 16 + kg * 4 + r;
        const int col = bcol + wc * 64 + ni * 16 + lr;
        float v = acc[mi][ni][r];
        if (col < 512) {                       // q
          v += qb[col];
          Qb[(size_t)row * 512 + col] = f2bf(v);
        } else if (col < 1024) {               // k
          const int c2 = col - 512;
          v += kb[c2];
          outK[(size_t)row * 512 + c2] = v;
          Kb[(size_t)row * 512 + c2] = f2bf(v);
        } else {                               // v
          const int c2 = col - 1024;
          v += vb[c2];
          outV[(size_t)row * 2048 + c2] = v;
          Vb[(size_t)row * 2048 + c2] = f2bf(v);
        }
      }
    }
  }
}

// ---------------------------------------------------------------------------
// 256^2 4-phase GEMM (r7-exact; scores GEMM, 2-D grid (16,16)).
// ---------------------------------------------------------------------------
__global__ __launch_bounds__(512, 2)
void gemm256_kernel(const unsigned short* __restrict__ A,
                    const unsigned short* __restrict__ B,
                    int M, int N, int K,
                    const float* __restrict__ bias,
                    const float* __restrict__ resid,
                    float scale, int relu,
                    float* __restrict__ outF,
                    unsigned short* __restrict__ outB)
{
  __shared__ __align__(16) unsigned short lds[2][2][2][128][64];  // 128 KiB

  const int tid  = threadIdx.x;
  const int lane = tid & 63;
  const int wave = tid >> 6;     // 0..7
  const int wm   = wave >> 2;    // 0..1  (128-row half)
  const int wn   = wave & 3;     // 0..3  (64-col strip)
  const int lr   = lane & 15;
  const int kg   = lane >> 4;
  const int brow = blockIdx.x * 256;
  const int bcol = blockIdx.y * 256;

  const int srow = tid >> 3;                              // 0..63
  const int ssw  = ((tid & 7) * 8) ^ ((srow & 7) << 3);   // pre-swizzled k
  const unsigned short* Asrc = A + (size_t)(brow + srow) * K + ssw;
  const unsigned short* Bsrc = B + (size_t)(bcol + srow) * K + ssw;

  char* lbase = (char*)&lds[0][0][0][0][0];
  const int woff = wave * 1024;

  f32x4 acc[8][4];
#pragma unroll
  for (int i = 0; i < 8; ++i)
#pragma unroll
    for (int j = 0; j < 4; ++j) acc[i][j] = (f32x4){0.f, 0.f, 0.f, 0.f};

  const int NT = K >> 6;

  auto SA = [&](int d, int h, int q, int tl) {
    __builtin_amdgcn_global_load_lds(
        (const g_void*)(Asrc + (size_t)(h * 128 + q * 64) * K + tl * 64),
        (lds_void*)(lbase + d * 32768 + h * 16384 + q * 8192 + woff), 16, 0, 0);
  };
  auto SB = [&](int d, int h, int q, int tl) {
    __builtin_amdgcn_global_load_lds(
        (const g_void*)(Bsrc + (size_t)(h * 128 + q * 64) * K + tl * 64),
        (lds_void*)(lbase + 65536 + d * 32768 + h * 16384 + q * 8192 + woff), 16, 0, 0);
  };

  auto LDA = [&](short8* a, int d, int mh, int ks) {
    const char* reg = lbase + d * 32768 + wm * 16384;
    const int ke = (ks * 32 + kg * 8) ^ ((lr & 7) << 3);
#pragma unroll
    for (int i = 0; i < 4; ++i) {
      const int row = (mh * 4 + i) * 16 + lr;
      a[i] = *(const short8*)(reg + row * 128 + ke * 2);
    }
  };
  auto LDB = [&](short8* b, int d, int ks) {
    const char* reg = lbase + 65536 + d * 32768 + (wn >> 1) * 16384;
    const int ke = (ks * 32 + kg * 8) ^ ((lr & 7) << 3);
#pragma unroll
    for (int n = 0; n < 4; ++n) {
      const int row = (wn & 1) * 64 + n * 16 + lr;
      b[n] = *(const short8*)(reg + row * 128 + ke * 2);
    }
  };

  auto MM = [&](int mh, short8* a, short8* b) {
    __builtin_amdgcn_s_setprio(1);
#pragma unroll
    for (int i = 0; i < 4; ++i)
#pragma unroll
      for (int n = 0; n < 4; ++n)
        acc[mh * 4 + i][n] = __builtin_amdgcn_mfma_f32_16x16x32_bf16(
            a[i], b[n], acc[mh * 4 + i][n], 0, 0, 0);
    __builtin_amdgcn_s_setprio(0);
  };

  SA(0, 0, 0, 0); SA(0, 0, 1, 0); SA(0, 1, 0, 0); SA(0, 1, 1, 0);
  SB(0, 0, 0, 0); SB(0, 0, 1, 0); SB(0, 1, 0, 0); SB(0, 1, 1, 0);
  SB(1, 0, 0, 1); SB(1, 0, 1, 1); SA(1, 0, 0, 1);
  SB(1, 1, 0, 1); SB(1, 1, 1, 1); SA(1, 1, 0, 1);
  VMCNT6();
  BARRIER();

  short8 aT[4], bF0[4], bF1[4];
  for (int t = 0; t < NT; ++t) {
    const int buf = t & 1, nb = buf ^ 1;
    const int t1 = (t + 1 < NT) ? t + 1 : NT - 1;
    const int t2 = (t + 2 < NT) ? t + 2 : NT - 1;

    LDA(aT, buf, 0, 0); LDB(bF0, buf, 0);
    SA(nb, 0, 1, t1); SA(nb, 1, 1, t1);
    BARRIER(); MM(0, aT, bF0); BARRIER();

    LDA(aT, buf, 0, 1); LDB(bF1, buf, 1);
    BARRIER(); MM(0, aT, bF1); BARRIER();

    LDA(aT, buf, 1, 0);
    SB(buf, 0, 0, t2); SB(buf, 0, 1, t2); SA(buf, 0, 0, t2);
    BARRIER(); MM(1, aT, bF0); BARRIER();

    LDA(aT, buf, 1, 1);
    SB(buf, 1, 0, t2); SB(buf, 1, 1, t2); SA(buf, 1, 0, t2);
    BARRIER(); MM(1, aT, bF1);
    VMCNT6();
    BARRIER();
  }
  VMCNT0();

#pragma unroll
  for (int mi = 0; mi < 8; ++mi) {
#pragma unroll
    for (int ni = 0; ni < 4; ++ni) {
#pragma unroll
      for (int r = 0; r < 4; ++r) {
        const int row = brow + wm * 128 + mi * 16 + kg * 4 + r;
        const int col = bcol + wn * 64 + ni * 16 + lr;
        float v = acc[mi][ni][r] * scale;
        if (bias)  v += bias[col];
        if (resid) v += resid[(size_t)row * N + col];
        if (relu)  v = fmaxf(v, 0.0f);
        if (outF)  outF[(size_t)row * N + col] = v;
        if (outB)  outB[(size_t)row * N + col] = f2bf(v);
      }
    }
  }
}

// ---------------------------------------------------------------------------
// 256x128 reg-double-buffered GEMM (r7-exact; grid (16,16)).
// ---------------------------------------------------------------------------
__global__ __launch_bounds__(512, 2)
void gemm256x128_kernel(const unsigned short* __restrict__ A,
                        const unsigned short* __restrict__ B,
                        int M, int N, int K,
                        const float* __restrict__ bias,
                        const float* __restrict__ resid,
                        float scale, int relu,
                        float* __restrict__ outF,
                        unsigned short* __restrict__ outB)
{
  __shared__ __align__(16) unsigned short lds[49152];   // 96 KiB

  const int tid  = threadIdx.x;
  const int lane = tid & 63;
  const int wave = tid >> 6;     // 0..7
  const int wm   = wave >> 1;    // 0..3  (64-row strip)
  const int wn   = wave & 1;     // 0..1  (64-col strip)
  const int lr   = lane & 15;
  const int kg   = lane >> 4;
  const int brow = blockIdx.x * 256;
  const int bcol = blockIdx.y * 128;

  const int srow = tid >> 3;                              // 0..63
  const int ssw  = ((tid & 7) * 8) ^ ((srow & 7) << 3);
  const unsigned short* Asrc = A + (size_t)(brow + srow) * K + ssw;
  const unsigned short* Bsrc = B + (size_t)(bcol + srow) * K + ssw;

  char* lbase = (char*)&lds[0];
  const int woff = wave * 1024;

  f32x4 acc[4][4];
#pragma unroll
  for (int i = 0; i < 4; ++i)
#pragma unroll
    for (int j = 0; j < 4; ++j) acc[i][j] = (f32x4){0.f, 0.f, 0.f, 0.f};

  const int NT = K >> 6;   // even for all call sites (K = 2048 / 4096)

  auto STAGE = [&](int d, int tl) {
#pragma unroll
    for (int r = 0; r < 4; ++r)
      __builtin_amdgcn_global_load_lds(
          (const g_void*)(Asrc + (size_t)(r * 64) * K + tl * 64),
          (lds_void*)(lbase + d * 32768 + r * 8192 + woff), 16, 0, 0);
#pragma unroll
    for (int r = 0; r < 2; ++r)
      __builtin_amdgcn_global_load_lds(
          (const g_void*)(Bsrc + (size_t)(r * 64) * K + tl * 64),
          (lds_void*)(lbase + 65536 + d * 16384 + r * 8192 + woff), 16, 0, 0);
  };

  auto RD = [&](short8* a, short8* b, int d) {
#pragma unroll
    for (int ks = 0; ks < 2; ++ks) {
      const int ke = (ks * 32 + kg * 8) ^ ((lr & 7) << 3);
      const char* ra = lbase + d * 32768;
      const char* rb = lbase + 65536 + d * 16384;
#pragma unroll
      for (int mi = 0; mi < 4; ++mi)
        a[ks * 4 + mi] = *(const short8*)(ra + (wm * 64 + mi * 16 + lr) * 128 + ke * 2);
#pragma unroll
      for (int n = 0; n < 4; ++n)
        b[ks * 4 + n] = *(const short8*)(rb + (wn * 64 + n * 16 + lr) * 128 + ke * 2);
    }
  };

  auto MMALL = [&](short8* a, short8* b) {
    __builtin_amdgcn_s_setprio(1);
#pragma unroll
    for (int ks = 0; ks < 2; ++ks)
#pragma unroll
      for (int mi = 0; mi < 4; ++mi)
#pragma unroll
        for (int n = 0; n < 4; ++n)
          acc[mi][n] = __builtin_amdgcn_mfma_f32_16x16x32_bf16(
              a[ks * 4 + mi], b[ks * 4 + n], acc[mi][n], 0, 0, 0);
    __builtin_amdgcn_s_setprio(0);
  };

  STAGE(0, 0);
  STAGE(1, 1);
  VMCNT0();
  BARRIER();
  short8 aE[8], bE[8], aO[8], bO[8];
  RD(aE, bE, 0);
  LGKM0();

  for (int t = 0; t < NT; t += 2) {
    VMCNT0();
    BARRIER();
    { const int t2 = (t + 2 < NT) ? t + 2 : NT - 1; STAGE(0, t2); }
    RD(aO, bO, 1);
    MMALL(aE, bE);
    LGKM0();
    VMCNT0();
    BARRIER();
    { const int t3 = (t + 3 < NT) ? t + 3 : NT - 1; STAGE(1, t3); }
    RD(aE, bE, 0);
    MMALL(aO, bO);
    LGKM0();
  }
  VMCNT0();

#pragma unroll
  for (int mi = 0; mi < 4; ++mi) {
#pragma unroll
    for (int ni = 0; ni < 4; ++ni) {
#pragma unroll
      for (int r = 0; r < 4; ++r) {
        const int row = brow + wm * 64 + mi * 16 + kg * 4 + r;
        const int col = bcol + wn * 64 + ni * 16 + lr;
        float v = acc[mi][ni][r] * scale;
        if (bias)  v += bias[col];
        if (resid) v += resid[(size_t)row * N + col];
        if (relu)  v = fmaxf(v, 0.0f);
        if (outF)  outF[(size_t)row * N + col] = v;
        if (outB)  outB[(size_t)row * N + col] = f2bf(v);
      }
    }
  }
}

// ---------------------------------------------------------------------------
// register-resident row softmax: one block per row, 16 elems/thread in regs.
// Load once (4x float4), max, exp, sum, store (4x ushort4).  No LDS buffer.
// ---------------------------------------------------------------------------
__global__ __launch_bounds__(256) void softmax_kernel(
    const float* __restrict__ Sc, unsigned short* __restrict__ P) {
  __shared__ float redm[4];
  __shared__ float reds[4];
  const int tid = threadIdx.x;
  const int row = blockIdx.x;
  const float* src = Sc + (size_t)row * SEQ;

  float4 f0 = *(const float4*)(src + tid * 4);
  float4 f1 = *(const float4*)(src + tid * 4 + 1024);
  float4 f2 = *(const float4*)(src + tid * 4 + 2048);
  float4 f3 = *(const float4*)(src + tid * 4 + 3072);

  float lmax = fmaxf(fmaxf(fmaxf(f0.x, f0.y), fmaxf(f0.z, f0.w)),
                     fmaxf(fmaxf(f1.x, f1.y), fmaxf(f1.z, f1.w)));
  lmax = fmaxf(lmax, fmaxf(fmaxf(f2.x, f2.y), fmaxf(f2.z, f2.w)));
  lmax = fmaxf(lmax, fmaxf(fmaxf(f3.x, f3.y), fmaxf(f3.z, f3.w)));
#pragma unroll
  for (int off = 32; off > 0; off >>= 1)
    lmax = fmaxf(lmax, __shfl_xor(lmax, off, 64));
  if ((tid & 63) == 0) redm[tid >> 6] = lmax;
  __syncthreads();
  const float m = fmaxf(fmaxf(redm[0], redm[1]), fmaxf(redm[2], redm[3]));

  f0.x = __expf(f0.x - m); f0.y = __expf(f0.y - m);
  f0.z = __expf(f0.z - m); f0.w = __expf(f0.w - m);
  f1.x = __expf(f1.x - m); f1.y = __expf(f1.y - m);
  f1.z = __expf(f1.z - m); f1.w = __expf(f1.w - m);
  f2.x = __expf(f2.x - m); f2.y = __expf(f2.y - m);
  f2.z = __expf(f2.z - m); f2.w = __expf(f2.w - m);
  f3.x = __expf(f3.x - m); f3.y = __expf(f3.y - m);
  f3.z = __expf(f3.z - m); f3.w = __expf(f3.w - m);

  float lsum = (f0.x + f0.y + f0.z + f0.w) + (f1.x + f1.y + f1.z + f1.w) +
               (f2.x + f2.y + f2.z + f2.w) + (f3.x + f3.y + f3.z + f3.w);
#pragma unroll
  for (int off = 32; off > 0; off >>= 1)
    lsum += __shfl_xor(lsum, off, 64);
  if ((tid & 63) == 0) reds[tid >> 6] = lsum;
  __syncthreads();
  const float inv = 1.0f / (reds[0] + reds[1] + reds[2] + reds[3]);

  unsigned short* dst = P + (size_t)row * SEQ;
  ushort4 o0 = { f2bf(f0.x * inv), f2bf(f0.y * inv), f2bf(f0.z * inv), f2bf(f0.w * inv) };
  ushort4 o1 = { f2bf(f1.x * inv), f2bf(f1.y * inv), f2bf(f1.z * inv), f2bf(f1.w * inv) };
  ushort4 o2 = { f2bf(f2.x * inv), f2bf(f2.y * inv), f2bf(f2.z * inv), f2bf(f2.w * inv) };
  ushort4 o3 = { f2bf(f3.x * inv), f2bf(f3.y * inv), f2bf(f3.z * inv), f2bf(f3.w * inv) };
  *(ushort4*)(dst + tid * 4)        = o0;
  *(ushort4*)(dst + tid * 4 + 1024) = o1;
  *(ushort4*)(dst + tid * 4 + 2048) = o2;
  *(ushort4*)(dst + tid * 4 + 3072) = o3;
}

// ---------------------------------------------------------------------------
// launch
// ---------------------------------------------------------------------------
extern "C" void kernel_launch(void* const* d_in, const int* in_sizes, int n_in,
                              void* d_out, int out_size, void* d_ws, size_t ws_size,
                              hipStream_t stream) {
  const float* x  = (const float*)d_in[0];
  const float* qw = (const float*)d_in[1];
  const float* qb = (const float*)d_in[2];
  const float* kw = (const float*)d_in[3];
  const float* kb = (const float*)d_in[4];
  const float* vw = (const float*)d_in[5];
  const float* vb = (const float*)d_in[6];
  const float* w1 = (const float*)d_in[7];
  const float* b1 = (const float*)d_in[8];
  const float* w2 = (const float*)d_in[9];
  const float* b2 = (const float*)d_in[10];
  float* out = (float*)d_out;   // [hidden(8388608) | k(2097152) | v(8388608)]
  char* ws = (char*)d_ws;

  const size_t MB = 1048576;
  unsigned short* Xb    = (unsigned short*)(ws + 0 * MB);    // 16M, dead after QKV
  unsigned short* QKVWb = (unsigned short*)(ws + 16 * MB);   // 12M [qw;kw;vw], dead after QKV
  unsigned short* Pb    = (unsigned short*)(ws + 0 * MB);    // 32M, overlays Xb+QKVWb
  unsigned short* W1b   = (unsigned short*)(ws + 32 * MB);   //  8M
  unsigned short* W2b   = (unsigned short*)(ws + 40 * MB);   //  8M
  unsigned short* Qb    = (unsigned short*)(ws + 48 * MB);   //  4M
  unsigned short* Kb    = (unsigned short*)(ws + 52 * MB);   //  4M
  unsigned short* Vb    = (unsigned short*)(ws + 56 * MB);   // 16M, dead after transpose
  unsigned short* VTb   = (unsigned short*)(ws + 72 * MB);   // 16M
  float*          Sc    = (float*)(ws + 88 * MB);            // 64M, dead after softmax
  float*          XR    = (float*)(ws + 88 * MB);            // 32M overlays dead Sc
  unsigned short* X1b   = (unsigned short*)(ws + 120 * MB);  // 16M overlays dead Sc
  unsigned short* XRb   = (unsigned short*)(ws + 136 * MB);  // 16M overlays dead Sc

  // casts to bf16 (QKVWb = [qw ; kw ; vw] rows concatenated)
  cast_bf16_kernel<<<8192, 256, 0, stream>>>(x,  Xb, 2097152);
  cast_bf16_kernel<<<1024, 256, 0, stream>>>(qw, QKVWb, 262144);
  cast_bf16_kernel<<<1024, 256, 0, stream>>>(kw, QKVWb + 512 * 2048, 262144);
  cast_bf16_kernel<<<4096, 256, 0, stream>>>(vw, QKVWb + 1024 * 2048, 1048576);
  cast_bf16_kernel<<<4096, 256, 0, stream>>>(w1, W1b, 1048576);
  cast_bf16_kernel<<<4096, 256, 0, stream>>>(w2, W2b, 1048576);

  // q,k,v = x @ [qw;kw;vw]^T + bias   (768 blocks = 3 blk/CU)
  gemm_qkv_kernel<<<dim3(32, 24), dim3(256), 0, stream>>>(
      Xb, QKVWb, SEQ, 3072, DMODEL, qb, kb, vb,
      out + 8388608, out + 10485760, Qb, Kb, Vb);
  // VTb = Vb^T  ([2048][4096])
  transpose_bf16_kernel<<<dim3(64, 32), dim3(256), 0, stream>>>(Vb, VTb, SEQ, DMODEL);
  // scores = (q @ k^T) / sqrt(512)  -> fp32
  gemm256_kernel<<<dim3(16, 16), dim3(512), 0, stream>>>(
      Qb, Kb, SEQ, SEQ, DINT, nullptr, nullptr,
      0.04419417382415922f, 0, Sc, nullptr);
  // P = softmax(scores)  -> bf16
  softmax_kernel<<<4096, dim3(256), 0, stream>>>(Sc, Pb);
  // x_residual = P @ V + x  -> fp32 + bf16
  gemm256x128_kernel<<<dim3(16, 16), dim3(512), 0, stream>>>(
      Pb, VTb, SEQ, DMODEL, SEQ, nullptr, x, 1.0f, 0, XR, XRb);
  // x1 = relu(x_residual @ w1^T + b1)  -> bf16
  gemm256x128_kernel<<<dim3(16, 16), dim3(512), 0, stream>>>(
      XRb, W1b, SEQ, DMODEL, DMODEL, b1, nullptr, 1.0f, 1, nullptr, X1b);
  // hidden = x1 @ w2^T + b2 + x_residual  -> fp32 (out)
  gemm256x128_kernel<<<dim3(16, 16), dim3(512), 0, stream>>>(
      X1b, W2b, SEQ, DMODEL, DMODEL, b2, XR, 1.0f, 0, out, nullptr);
}

// Round 11
// 359.401 us; speedup vs baseline: 1.5626x; 1.0620x over previous
//
#include <hip/hip_runtime.h>
#include <cstdint>
#include <cstddef>

// ---------------------------------------------------------------------------
// TransformerLayer: hidden,k,v = f(x, qw,qb, kw,kb, vw,vb, w1,b1, w2,b2)
// S=4096, D_MODEL=2048, D_INT=512.  bf16 MFMA GEMMs, fp32 accumulate.
// Round 11: QKV fused GEMM rebuilt with BK=32 double-buffer -> 32 KiB LDS
// -> 3 blocks/CU co-resident at grid 768 (the m102/m103 high-TLP regime).
// Everything else at the r10-measured state.
// ---------------------------------------------------------------------------

typedef __attribute__((ext_vector_type(8))) short short8;   // 8 x bf16 bits
typedef __attribute__((ext_vector_type(4))) float f32x4;    // MFMA accum

typedef __attribute__((address_space(3))) void lds_void;
typedef __attribute__((address_space(1))) void g_void;

#define SEQ    4096
#define DMODEL 2048
#define DINT   512

#define MEMF() asm volatile("" ::: "memory")
#define BARRIER() do { MEMF(); __builtin_amdgcn_s_barrier(); MEMF(); } while (0)
#define VMCNT6() asm volatile("s_waitcnt vmcnt(6)" ::: "memory")
#define VMCNT0() asm volatile("s_waitcnt vmcnt(0)" ::: "memory")
#define LGKM0()  asm volatile("s_waitcnt lgkmcnt(0)" ::: "memory")

// fp32 -> bf16 bits, round-to-nearest-even
__device__ __forceinline__ unsigned short f2bf(float f) {
  union { float f; unsigned int u; } a;
  a.f = f;
  unsigned int u = a.u;
  u += 0x7fffu + ((u >> 16) & 1u);
  return (unsigned short)(u >> 16);
}

// ---------------------------------------------------------------------------
// cast: fp32 -> bf16 (4 elems / thread)
// ---------------------------------------------------------------------------
__global__ __launch_bounds__(256) void cast_bf16_kernel(
    const float* __restrict__ in, unsigned short* __restrict__ out, int n4) {
  int i = blockIdx.x * 256 + threadIdx.x;
  if (i >= n4) return;
  float4 v = ((const float4*)in)[i];
  ushort4 o;
  o.x = f2bf(v.x); o.y = f2bf(v.y); o.z = f2bf(v.z); o.w = f2bf(v.w);
  ((ushort4*)out)[i] = o;
}

// ---------------------------------------------------------------------------
// bf16 transpose: out[C][R] = in[R][C].  64x64 LDS tile.
// ---------------------------------------------------------------------------
__global__ __launch_bounds__(256) void transpose_bf16_kernel(
    const unsigned short* __restrict__ in, unsigned short* __restrict__ out,
    int R, int C) {
  __shared__ unsigned short tile[64][65];
  const int tx = threadIdx.x & 63;
  const int ty = threadIdx.x >> 6;
  const int r0 = blockIdx.x * 64;
  const int c0 = blockIdx.y * 64;
#pragma unroll
  for (int i = 0; i < 64; i += 4)
    tile[ty + i][tx] = in[(size_t)(r0 + ty + i) * C + c0 + tx];
  __syncthreads();
#pragma unroll
  for (int i = 0; i < 64; i += 4)
    out[(size_t)(c0 + ty + i) * R + r0 + tx] = tile[tx][ty + i];
}

// ---------------------------------------------------------------------------
// Fused QKV GEMM: 2-phase 128^2, BK=32 double-buffered (32 KiB LDS ->
// 5 blk/CU LDS-cap; grid (32,24)=768 -> 3 blk/CU co-resident).
// A=[4096,2048] bf16, W=[3072,2048] bf16 ([qw;kw;vw]).
// Per 32-K tile: 4 global_load_lds (prefetch t+1) + 8 ds_read_b128 +
// 16 MFMA per wave + 1 __syncthreads.
// Epilogue segments (block-uniform, boundaries at 512/1024):
//   col <  512 : q -> Qb bf16                 (stride 512)
//   col < 1024 : k -> outK fp32 + Kb bf16     (stride 512)
//   else       : v -> outV fp32 + Vb bf16     (stride 2048)
// ---------------------------------------------------------------------------
__global__ __launch_bounds__(256)
void gemm_qkv_kernel(const unsigned short* __restrict__ A,
                     const unsigned short* __restrict__ W,
                     int M, int N, int K,
                     const float* __restrict__ qb,
                     const float* __restrict__ kb,
                     const float* __restrict__ vb,
                     float* __restrict__ outK,
                     float* __restrict__ outV,
                     unsigned short* __restrict__ Qb,
                     unsigned short* __restrict__ Kb,
                     unsigned short* __restrict__ Vb)
{
  __shared__ __align__(16) unsigned short As[2][128][32];   // 2 x 8 KiB
  __shared__ __align__(16) unsigned short Bs[2][128][32];   // 2 x 8 KiB

  const int tid  = threadIdx.x;
  const int lane = tid & 63;
  const int wave = tid >> 6;
  const int wr   = wave >> 1;
  const int wc   = wave & 1;
  const int brow = blockIdx.x * 128;
  const int bcol = blockIdx.y * 128;
  const int lr   = lane & 15;
  const int kg   = lane >> 4;

  // staging: row = 32 bf16 = 64 B = 4 lanes x 16 B; one block-wide glds
  // (256 thr x 16 B = 4 KiB) covers 64 rows; 2 chunks per operand.
  const int srow  = tid >> 2;          // 0..63
  const int scol  = (tid & 3) * 8;
  const int wbase = wave * 16;         // wave-uniform row base within chunk
  const unsigned short* Ab = A + (size_t)(brow + srow) * K + scol;
  const unsigned short* Bb = W + (size_t)(bcol + srow) * K + scol;

  f32x4 acc[4][4];
#pragma unroll
  for (int i = 0; i < 4; i++)
#pragma unroll
    for (int j = 0; j < 4; j++) acc[i][j] = (f32x4){0.f, 0.f, 0.f, 0.f};

  auto stage = [&](int d, int k0) {
#pragma unroll
    for (int j = 0; j < 2; ++j) {
      __builtin_amdgcn_global_load_lds((const g_void*)(Ab + (size_t)(j * 64) * K + k0),
                                       (lds_void*)&As[d][j * 64 + wbase][0], 16, 0, 0);
      __builtin_amdgcn_global_load_lds((const g_void*)(Bb + (size_t)(j * 64) * K + k0),
                                       (lds_void*)&Bs[d][j * 64 + wbase][0], 16, 0, 0);
    }
  };

  auto compute = [&](int d) {
    short8 aF[4], bF[4];
#pragma unroll
    for (int mi = 0; mi < 4; ++mi)
      aF[mi] = *(const short8*)&As[d][wr * 64 + mi * 16 + lr][kg * 8];
#pragma unroll
    for (int ni = 0; ni < 4; ++ni)
      bF[ni] = *(const short8*)&Bs[d][wc * 64 + ni * 16 + lr][kg * 8];
#pragma unroll
    for (int mi = 0; mi < 4; ++mi)
#pragma unroll
      for (int ni = 0; ni < 4; ++ni)
        acc[mi][ni] = __builtin_amdgcn_mfma_f32_16x16x32_bf16(
            aF[mi], bF[ni], acc[mi][ni], 0, 0, 0);
  };

  stage(0, 0);
  __syncthreads();
  int c = 0;
  const int NT = K >> 5;     // 64 tiles of 32
  for (int t = 0; t < NT; ++t) {
    if (t + 1 < NT) stage(c ^ 1, (t + 1) << 5);
    compute(c);
    __syncthreads();
    c ^= 1;
  }

#pragma unroll
  for (int mi = 0; mi < 4; mi++) {
#pragma unroll
    for (int ni = 0; ni < 4; ni++) {
#pragma unroll
      for (int r = 0; r < 4; r++) {
        const int row = brow + wr * 64 + mi * 16 + kg * 4 + r;
        const int col = bcol + wc * 64 + ni * 16 + lr;
        float v = acc[mi][ni][r];
        if (col < 512) {                       // q
          v += qb[col];
          Qb[(size_t)row * 512 + col] = f2bf(v);
        } else if (col < 1024) {               // k
          const int c2 = col - 512;
          v += kb[c2];
          outK[(size_t)row * 512 + c2] = v;
          Kb[(size_t)row * 512 + c2] = f2bf(v);
        } else {                               // v
          const int c2 = col - 1024;
          v += vb[c2];
          outV[(size_t)row * 2048 + c2] = v;
          Vb[(size_t)row * 2048 + c2] = f2bf(v);
        }
      }
    }
  }
}

// ---------------------------------------------------------------------------
// 256^2 4-phase GEMM (r7-exact; scores GEMM, 2-D grid (16,16)).
// ---------------------------------------------------------------------------
__global__ __launch_bounds__(512, 2)
void gemm256_kernel(const unsigned short* __restrict__ A,
                    const unsigned short* __restrict__ B,
                    int M, int N, int K,
                    const float* __restrict__ bias,
                    const float* __restrict__ resid,
                    float scale, int relu,
                    float* __restrict__ outF,
                    unsigned short* __restrict__ outB)
{
  __shared__ __align__(16) unsigned short lds[2][2][2][128][64];  // 128 KiB

  const int tid  = threadIdx.x;
  const int lane = tid & 63;
  const int wave = tid >> 6;     // 0..7
  const int wm   = wave >> 2;    // 0..1  (128-row half)
  const int wn   = wave & 3;     // 0..3  (64-col strip)
  const int lr   = lane & 15;
  const int kg   = lane >> 4;
  const int brow = blockIdx.x * 256;
  const int bcol = blockIdx.y * 256;

  const int srow = tid >> 3;                              // 0..63
  const int ssw  = ((tid & 7) * 8) ^ ((srow & 7) << 3);   // pre-swizzled k
  const unsigned short* Asrc = A + (size_t)(brow + srow) * K + ssw;
  const unsigned short* Bsrc = B + (size_t)(bcol + srow) * K + ssw;

  char* lbase = (char*)&lds[0][0][0][0][0];
  const int woff = wave * 1024;

  f32x4 acc[8][4];
#pragma unroll
  for (int i = 0; i < 8; ++i)
#pragma unroll
    for (int j = 0; j < 4; ++j) acc[i][j] = (f32x4){0.f, 0.f, 0.f, 0.f};

  const int NT = K >> 6;

  auto SA = [&](int d, int h, int q, int tl) {
    __builtin_amdgcn_global_load_lds(
        (const g_void*)(Asrc + (size_t)(h * 128 + q * 64) * K + tl * 64),
        (lds_void*)(lbase + d * 32768 + h * 16384 + q * 8192 + woff), 16, 0, 0);
  };
  auto SB = [&](int d, int h, int q, int tl) {
    __builtin_amdgcn_global_load_lds(
        (const g_void*)(Bsrc + (size_t)(h * 128 + q * 64) * K + tl * 64),
        (lds_void*)(lbase + 65536 + d * 32768 + h * 16384 + q * 8192 + woff), 16, 0, 0);
  };

  auto LDA = [&](short8* a, int d, int mh, int ks) {
    const char* reg = lbase + d * 32768 + wm * 16384;
    const int ke = (ks * 32 + kg * 8) ^ ((lr & 7) << 3);
#pragma unroll
    for (int i = 0; i < 4; ++i) {
      const int row = (mh * 4 + i) * 16 + lr;
      a[i] = *(const short8*)(reg + row * 128 + ke * 2);
    }
  };
  auto LDB = [&](short8* b, int d, int ks) {
    const char* reg = lbase + 65536 + d * 32768 + (wn >> 1) * 16384;
    const int ke = (ks * 32 + kg * 8) ^ ((lr & 7) << 3);
#pragma unroll
    for (int n = 0; n < 4; ++n) {
      const int row = (wn & 1) * 64 + n * 16 + lr;
      b[n] = *(const short8*)(reg + row * 128 + ke * 2);
    }
  };

  auto MM = [&](int mh, short8* a, short8* b) {
    __builtin_amdgcn_s_setprio(1);
#pragma unroll
    for (int i = 0; i < 4; ++i)
#pragma unroll
      for (int n = 0; n < 4; ++n)
        acc[mh * 4 + i][n] = __builtin_amdgcn_mfma_f32_16x16x32_bf16(
            a[i], b[n], acc[mh * 4 + i][n], 0, 0, 0);
    __builtin_amdgcn_s_setprio(0);
  };

  SA(0, 0, 0, 0); SA(0, 0, 1, 0); SA(0, 1, 0, 0); SA(0, 1, 1, 0);
  SB(0, 0, 0, 0); SB(0, 0, 1, 0); SB(0, 1, 0, 0); SB(0, 1, 1, 0);
  SB(1, 0, 0, 1); SB(1, 0, 1, 1); SA(1, 0, 0, 1);
  SB(1, 1, 0, 1); SB(1, 1, 1, 1); SA(1, 1, 0, 1);
  VMCNT6();
  BARRIER();

  short8 aT[4], bF0[4], bF1[4];
  for (int t = 0; t < NT; ++t) {
    const int buf = t & 1, nb = buf ^ 1;
    const int t1 = (t + 1 < NT) ? t + 1 : NT - 1;
    const int t2 = (t + 2 < NT) ? t + 2 : NT - 1;

    LDA(aT, buf, 0, 0); LDB(bF0, buf, 0);
    SA(nb, 0, 1, t1); SA(nb, 1, 1, t1);
    BARRIER(); MM(0, aT, bF0); BARRIER();

    LDA(aT, buf, 0, 1); LDB(bF1, buf, 1);
    BARRIER(); MM(0, aT, bF1); BARRIER();

    LDA(aT, buf, 1, 0);
    SB(buf, 0, 0, t2); SB(buf, 0, 1, t2); SA(buf, 0, 0, t2);
    BARRIER(); MM(1, aT, bF0); BARRIER();

    LDA(aT, buf, 1, 1);
    SB(buf, 1, 0, t2); SB(buf, 1, 1, t2); SA(buf, 1, 0, t2);
    BARRIER(); MM(1, aT, bF1);
    VMCNT6();
    BARRIER();
  }
  VMCNT0();

#pragma unroll
  for (int mi = 0; mi < 8; ++mi) {
#pragma unroll
    for (int ni = 0; ni < 4; ++ni) {
#pragma unroll
      for (int r = 0; r < 4; ++r) {
        const int row = brow + wm * 128 + mi * 16 + kg * 4 + r;
        const int col = bcol + wn * 64 + ni * 16 + lr;
        float v = acc[mi][ni][r] * scale;
        if (bias)  v += bias[col];
        if (resid) v += resid[(size_t)row * N + col];
        if (relu)  v = fmaxf(v, 0.0f);
        if (outF)  outF[(size_t)row * N + col] = v;
        if (outB)  outB[(size_t)row * N + col] = f2bf(v);
      }
    }
  }
}

// ---------------------------------------------------------------------------
// 256x128 reg-double-buffered GEMM (r7-exact; grid (16,16)).
// ---------------------------------------------------------------------------
__global__ __launch_bounds__(512, 2)
void gemm256x128_kernel(const unsigned short* __restrict__ A,
                        const unsigned short* __restrict__ B,
                        int M, int N, int K,
                        const float* __restrict__ bias,
                        const float* __restrict__ resid,
                        float scale, int relu,
                        float* __restrict__ outF,
                        unsigned short* __restrict__ outB)
{
  __shared__ __align__(16) unsigned short lds[49152];   // 96 KiB

  const int tid  = threadIdx.x;
  const int lane = tid & 63;
  const int wave = tid >> 6;     // 0..7
  const int wm   = wave >> 1;    // 0..3  (64-row strip)
  const int wn   = wave & 1;     // 0..1  (64-col strip)
  const int lr   = lane & 15;
  const int kg   = lane >> 4;
  const int brow = blockIdx.x * 256;
  const int bcol = blockIdx.y * 128;

  const int srow = tid >> 3;                              // 0..63
  const int ssw  = ((tid & 7) * 8) ^ ((srow & 7) << 3);
  const unsigned short* Asrc = A + (size_t)(brow + srow) * K + ssw;
  const unsigned short* Bsrc = B + (size_t)(bcol + srow) * K + ssw;

  char* lbase = (char*)&lds[0];
  const int woff = wave * 1024;

  f32x4 acc[4][4];
#pragma unroll
  for (int i = 0; i < 4; ++i)
#pragma unroll
    for (int j = 0; j < 4; ++j) acc[i][j] = (f32x4){0.f, 0.f, 0.f, 0.f};

  const int NT = K >> 6;   // even for all call sites (K = 2048 / 4096)

  auto STAGE = [&](int d, int tl) {
#pragma unroll
    for (int r = 0; r < 4; ++r)
      __builtin_amdgcn_global_load_lds(
          (const g_void*)(Asrc + (size_t)(r * 64) * K + tl * 64),
          (lds_void*)(lbase + d * 32768 + r * 8192 + woff), 16, 0, 0);
#pragma unroll
    for (int r = 0; r < 2; ++r)
      __builtin_amdgcn_global_load_lds(
          (const g_void*)(Bsrc + (size_t)(r * 64) * K + tl * 64),
          (lds_void*)(lbase + 65536 + d * 16384 + r * 8192 + woff), 16, 0, 0);
  };

  auto RD = [&](short8* a, short8* b, int d) {
#pragma unroll
    for (int ks = 0; ks < 2; ++ks) {
      const int ke = (ks * 32 + kg * 8) ^ ((lr & 7) << 3);
      const char* ra = lbase + d * 32768;
      const char* rb = lbase + 65536 + d * 16384;
#pragma unroll
      for (int mi = 0; mi < 4; ++mi)
        a[ks * 4 + mi] = *(const short8*)(ra + (wm * 64 + mi * 16 + lr) * 128 + ke * 2);
#pragma unroll
      for (int n = 0; n < 4; ++n)
        b[ks * 4 + n] = *(const short8*)(rb + (wn * 64 + n * 16 + lr) * 128 + ke * 2);
    }
  };

  auto MMALL = [&](short8* a, short8* b) {
    __builtin_amdgcn_s_setprio(1);
#pragma unroll
    for (int ks = 0; ks < 2; ++ks)
#pragma unroll
      for (int mi = 0; mi < 4; ++mi)
#pragma unroll
        for (int n = 0; n < 4; ++n)
          acc[mi][n] = __builtin_amdgcn_mfma_f32_16x16x32_bf16(
              a[ks * 4 + mi], b[ks * 4 + n], acc[mi][n], 0, 0, 0);
    __builtin_amdgcn_s_setprio(0);
  };

  STAGE(0, 0);
  STAGE(1, 1);
  VMCNT0();
  BARRIER();
  short8 aE[8], bE[8], aO[8], bO[8];
  RD(aE, bE, 0);
  LGKM0();

  for (int t = 0; t < NT; t += 2) {
    VMCNT0();
    BARRIER();
    { const int t2 = (t + 2 < NT) ? t + 2 : NT - 1; STAGE(0, t2); }
    RD(aO, bO, 1);
    MMALL(aE, bE);
    LGKM0();
    VMCNT0();
    BARRIER();
    { const int t3 = (t + 3 < NT) ? t + 3 : NT - 1; STAGE(1, t3); }
    RD(aE, bE, 0);
    MMALL(aO, bO);
    LGKM0();
  }
  VMCNT0();

#pragma unroll
  for (int mi = 0; mi < 4; ++mi) {
#pragma unroll
    for (int ni = 0; ni < 4; ++ni) {
#pragma unroll
      for (int r = 0; r < 4; ++r) {
        const int row = brow + wm * 64 + mi * 16 + kg * 4 + r;
        const int col = bcol + wn * 64 + ni * 16 + lr;
        float v = acc[mi][ni][r] * scale;
        if (bias)  v += bias[col];
        if (resid) v += resid[(size_t)row * N + col];
        if (relu)  v = fmaxf(v, 0.0f);
        if (outF)  outF[(size_t)row * N + col] = v;
        if (outB)  outB[(size_t)row * N + col] = f2bf(v);
      }
    }
  }
}

// ---------------------------------------------------------------------------
// register-resident row softmax: one block per row, 16 elems/thread in regs.
// ---------------------------------------------------------------------------
__global__ __launch_bounds__(256) void softmax_kernel(
    const float* __restrict__ Sc, unsigned short* __restrict__ P) {
  __shared__ float redm[4];
  __shared__ float reds[4];
  const int tid = threadIdx.x;
  const int row = blockIdx.x;
  const float* src = Sc + (size_t)row * SEQ;

  float4 f0 = *(const float4*)(src + tid * 4);
  float4 f1 = *(const float4*)(src + tid * 4 + 1024);
  float4 f2 = *(const float4*)(src + tid * 4 + 2048);
  float4 f3 = *(const float4*)(src + tid * 4 + 3072);

  float lmax = fmaxf(fmaxf(fmaxf(f0.x, f0.y), fmaxf(f0.z, f0.w)),
                     fmaxf(fmaxf(f1.x, f1.y), fmaxf(f1.z, f1.w)));
  lmax = fmaxf(lmax, fmaxf(fmaxf(f2.x, f2.y), fmaxf(f2.z, f2.w)));
  lmax = fmaxf(lmax, fmaxf(fmaxf(f3.x, f3.y), fmaxf(f3.z, f3.w)));
#pragma unroll
  for (int off = 32; off > 0; off >>= 1)
    lmax = fmaxf(lmax, __shfl_xor(lmax, off, 64));
  if ((tid & 63) == 0) redm[tid >> 6] = lmax;
  __syncthreads();
  const float m = fmaxf(fmaxf(redm[0], redm[1]), fmaxf(redm[2], redm[3]));

  f0.x = __expf(f0.x - m); f0.y = __expf(f0.y - m);
  f0.z = __expf(f0.z - m); f0.w = __expf(f0.w - m);
  f1.x = __expf(f1.x - m); f1.y = __expf(f1.y - m);
  f1.z = __expf(f1.z - m); f1.w = __expf(f1.w - m);
  f2.x = __expf(f2.x - m); f2.y = __expf(f2.y - m);
  f2.z = __expf(f2.z - m); f2.w = __expf(f2.w - m);
  f3.x = __expf(f3.x - m); f3.y = __expf(f3.y - m);
  f3.z = __expf(f3.z - m); f3.w = __expf(f3.w - m);

  float lsum = (f0.x + f0.y + f0.z + f0.w) + (f1.x + f1.y + f1.z + f1.w) +
               (f2.x + f2.y + f2.z + f2.w) + (f3.x + f3.y + f3.z + f3.w);
#pragma unroll
  for (int off = 32; off > 0; off >>= 1)
    lsum += __shfl_xor(lsum, off, 64);
  if ((tid & 63) == 0) reds[tid >> 6] = lsum;
  __syncthreads();
  const float inv = 1.0f / (reds[0] + reds[1] + reds[2] + reds[3]);

  unsigned short* dst = P + (size_t)row * SEQ;
  ushort4 o0 = { f2bf(f0.x * inv), f2bf(f0.y * inv), f2bf(f0.z * inv), f2bf(f0.w * inv) };
  ushort4 o1 = { f2bf(f1.x * inv), f2bf(f1.y * inv), f2bf(f1.z * inv), f2bf(f1.w * inv) };
  ushort4 o2 = { f2bf(f2.x * inv), f2bf(f2.y * inv), f2bf(f2.z * inv), f2bf(f2.w * inv) };
  ushort4 o3 = { f2bf(f3.x * inv), f2bf(f3.y * inv), f2bf(f3.z * inv), f2bf(f3.w * inv) };
  *(ushort4*)(dst + tid * 4)        = o0;
  *(ushort4*)(dst + tid * 4 + 1024) = o1;
  *(ushort4*)(dst + tid * 4 + 2048) = o2;
  *(ushort4*)(dst + tid * 4 + 3072) = o3;
}

// ---------------------------------------------------------------------------
// launch
// ---------------------------------------------------------------------------
extern "C" void kernel_launch(void* const* d_in, const int* in_sizes, int n_in,
                              void* d_out, int out_size, void* d_ws, size_t ws_size,
                              hipStream_t stream) {
  const float* x  = (const float*)d_in[0];
  const float* qw = (const float*)d_in[1];
  const float* qb = (const float*)d_in[2];
  const float* kw = (const float*)d_in[3];
  const float* kb = (const float*)d_in[4];
  const float* vw = (const float*)d_in[5];
  const float* vb = (const float*)d_in[6];
  const float* w1 = (const float*)d_in[7];
  const float* b1 = (const float*)d_in[8];
  const float* w2 = (const float*)d_in[9];
  const float* b2 = (const float*)d_in[10];
  float* out = (float*)d_out;   // [hidden(8388608) | k(2097152) | v(8388608)]
  char* ws = (char*)d_ws;

  const size_t MB = 1048576;
  unsigned short* Xb    = (unsigned short*)(ws + 0 * MB);    // 16M, dead after QKV
  unsigned short* QKVWb = (unsigned short*)(ws + 16 * MB);   // 12M [qw;kw;vw], dead after QKV
  unsigned short* Pb    = (unsigned short*)(ws + 0 * MB);    // 32M, overlays Xb+QKVWb
  unsigned short* W1b   = (unsigned short*)(ws + 32 * MB);   //  8M
  unsigned short* W2b   = (unsigned short*)(ws + 40 * MB);   //  8M
  unsigned short* Qb    = (unsigned short*)(ws + 48 * MB);   //  4M
  unsigned short* Kb    = (unsigned short*)(ws + 52 * MB);   //  4M
  unsigned short* Vb    = (unsigned short*)(ws + 56 * MB);   // 16M, dead after transpose
  unsigned short* VTb   = (unsigned short*)(ws + 72 * MB);   // 16M
  float*          Sc    = (float*)(ws + 88 * MB);            // 64M, dead after softmax
  float*          XR    = (float*)(ws + 88 * MB);            // 32M overlays dead Sc
  unsigned short* X1b   = (unsigned short*)(ws + 120 * MB);  // 16M overlays dead Sc
  unsigned short* XRb   = (unsigned short*)(ws + 136 * MB);  // 16M overlays dead Sc

  // casts to bf16 (QKVWb = [qw ; kw ; vw] rows concatenated)
  cast_bf16_kernel<<<8192, 256, 0, stream>>>(x,  Xb, 2097152);
  cast_bf16_kernel<<<1024, 256, 0, stream>>>(qw, QKVWb, 262144);
  cast_bf16_kernel<<<1024, 256, 0, stream>>>(kw, QKVWb + 512 * 2048, 262144);
  cast_bf16_kernel<<<4096, 256, 0, stream>>>(vw, QKVWb + 1024 * 2048, 1048576);
  cast_bf16_kernel<<<4096, 256, 0, stream>>>(w1, W1b, 1048576);
  cast_bf16_kernel<<<4096, 256, 0, stream>>>(w2, W2b, 1048576);

  // q,k,v = x @ [qw;kw;vw]^T + bias   (768 blocks, 3 blk/CU co-resident)
  gemm_qkv_kernel<<<dim3(32, 24), dim3(256), 0, stream>>>(
      Xb, QKVWb, SEQ, 3072, DMODEL, qb, kb, vb,
      out + 8388608, out + 10485760, Qb, Kb, Vb);
  // VTb = Vb^T  ([2048][4096])
  transpose_bf16_kernel<<<dim3(64, 32), dim3(256), 0, stream>>>(Vb, VTb, SEQ, DMODEL);
  // scores = (q @ k^T) / sqrt(512)  -> fp32
  gemm256_kernel<<<dim3(16, 16), dim3(512), 0, stream>>>(
      Qb, Kb, SEQ, SEQ, DINT, nullptr, nullptr,
      0.04419417382415922f, 0, Sc, nullptr);
  // P = softmax(scores)  -> bf16
  softmax_kernel<<<4096, dim3(256), 0, stream>>>(Sc, Pb);
  // x_residual = P @ V + x  -> fp32 + bf16
  gemm256x128_kernel<<<dim3(16, 16), dim3(512), 0, stream>>>(
      Pb, VTb, SEQ, DMODEL, SEQ, nullptr, x, 1.0f, 0, XR, XRb);
  // x1 = relu(x_residual @ w1^T + b1)  -> bf16
  gemm256x128_kernel<<<dim3(16, 16), dim3(512), 0, stream>>>(
      XRb, W1b, SEQ, DMODEL, DMODEL, b1, nullptr, 1.0f, 1, nullptr, X1b);
  // hidden = x1 @ w2^T + b2 + x_residual  -> fp32 (out)
  gemm256x128_kernel<<<dim3(16, 16), dim3(512), 0, stream>>>(
      X1b, W2b, SEQ, DMODEL, DMODEL, b2, XR, 1.0f, 0, out, nullptr);
}

// Round 12
// 345.663 us; speedup vs baseline: 1.6247x; 1.0397x over previous
//
#include <hip/hip_runtime.h>
#include <cstdint>
#include <cstddef>

// ---------------------------------------------------------------------------
// TransformerLayer: hidden,k,v = f(x, qw,qb, kw,kb, vw,vb, w1,b1, w2,b2)
// S=4096, D_MODEL=2048, D_INT=512.  bf16 MFMA GEMMs, fp32 accumulate.
// Round 12: (1) bf16 scores (halve Sc round-trip), (2) clean A/B of the
// 3-buffer counted-vmcnt x128 pipeline (no XCD swizzle) on P-V only;
// FF1/FF2 stay on the r7 2-buffer kernel as in-round control.
// ---------------------------------------------------------------------------

typedef __attribute__((ext_vector_type(8))) short short8;   // 8 x bf16 bits
typedef __attribute__((ext_vector_type(4))) float f32x4;    // MFMA accum

typedef __attribute__((address_space(3))) void lds_void;
typedef __attribute__((address_space(1))) void g_void;

#define SEQ    4096
#define DMODEL 2048
#define DINT   512

#define MEMF() asm volatile("" ::: "memory")
#define BARRIER() do { MEMF(); __builtin_amdgcn_s_barrier(); MEMF(); } while (0)
#define VMCNT12() asm volatile("s_waitcnt vmcnt(12)" ::: "memory")
#define VMCNT6() asm volatile("s_waitcnt vmcnt(6)" ::: "memory")
#define VMCNT0() asm volatile("s_waitcnt vmcnt(0)" ::: "memory")
#define LGKM0()  asm volatile("s_waitcnt lgkmcnt(0)" ::: "memory")

// fp32 -> bf16 bits, round-to-nearest-even
__device__ __forceinline__ unsigned short f2bf(float f) {
  union { float f; unsigned int u; } a;
  a.f = f;
  unsigned int u = a.u;
  u += 0x7fffu + ((u >> 16) & 1u);
  return (unsigned short)(u >> 16);
}
__device__ __forceinline__ float bf2f(unsigned short u) {
  union { unsigned int i; float f; } a;
  a.i = ((unsigned int)u) << 16;
  return a.f;
}

// ---------------------------------------------------------------------------
// cast: fp32 -> bf16 (4 elems / thread)
// ---------------------------------------------------------------------------
__global__ __launch_bounds__(256) void cast_bf16_kernel(
    const float* __restrict__ in, unsigned short* __restrict__ out, int n4) {
  int i = blockIdx.x * 256 + threadIdx.x;
  if (i >= n4) return;
  float4 v = ((const float4*)in)[i];
  ushort4 o;
  o.x = f2bf(v.x); o.y = f2bf(v.y); o.z = f2bf(v.z); o.w = f2bf(v.w);
  ((ushort4*)out)[i] = o;
}

// ---------------------------------------------------------------------------
// bf16 transpose: out[C][R] = in[R][C].  64x64 LDS tile.
// ---------------------------------------------------------------------------
__global__ __launch_bounds__(256) void transpose_bf16_kernel(
    const unsigned short* __restrict__ in, unsigned short* __restrict__ out,
    int R, int C) {
  __shared__ unsigned short tile[64][65];
  const int tx = threadIdx.x & 63;
  const int ty = threadIdx.x >> 6;
  const int r0 = blockIdx.x * 64;
  const int c0 = blockIdx.y * 64;
#pragma unroll
  for (int i = 0; i < 64; i += 4)
    tile[ty + i][tx] = in[(size_t)(r0 + ty + i) * C + c0 + tx];
  __syncthreads();
#pragma unroll
  for (int i = 0; i < 64; i += 4)
    out[(size_t)(c0 + ty + i) * R + r0 + tx] = tile[tx][ty + i];
}

// ---------------------------------------------------------------------------
// Fused QKV GEMM: 2-phase 128^2, BK=32 double-buffered (32 KiB LDS,
// grid (32,24)=768 -> 3 blk/CU co-resident).  r11-exact.
// ---------------------------------------------------------------------------
__global__ __launch_bounds__(256)
void gemm_qkv_kernel(const unsigned short* __restrict__ A,
                     const unsigned short* __restrict__ W,
                     int M, int N, int K,
                     const float* __restrict__ qb,
                     const float* __restrict__ kb,
                     const float* __restrict__ vb,
                     float* __restrict__ outK,
                     float* __restrict__ outV,
                     unsigned short* __restrict__ Qb,
                     unsigned short* __restrict__ Kb,
                     unsigned short* __restrict__ Vb)
{
  __shared__ __align__(16) unsigned short As[2][128][32];   // 2 x 8 KiB
  __shared__ __align__(16) unsigned short Bs[2][128][32];   // 2 x 8 KiB

  const int tid  = threadIdx.x;
  const int lane = tid & 63;
  const int wave = tid >> 6;
  const int wr   = wave >> 1;
  const int wc   = wave & 1;
  const int brow = blockIdx.x * 128;
  const int bcol = blockIdx.y * 128;
  const int lr   = lane & 15;
  const int kg   = lane >> 4;

  const int srow  = tid >> 2;          // 0..63
  const int scol  = (tid & 3) * 8;
  const int wbase = wave * 16;
  const unsigned short* Ab = A + (size_t)(brow + srow) * K + scol;
  const unsigned short* Bb = W + (size_t)(bcol + srow) * K + scol;

  f32x4 acc[4][4];
#pragma unroll
  for (int i = 0; i < 4; i++)
#pragma unroll
    for (int j = 0; j < 4; j++) acc[i][j] = (f32x4){0.f, 0.f, 0.f, 0.f};

  auto stage = [&](int d, int k0) {
#pragma unroll
    for (int j = 0; j < 2; ++j) {
      __builtin_amdgcn_global_load_lds((const g_void*)(Ab + (size_t)(j * 64) * K + k0),
                                       (lds_void*)&As[d][j * 64 + wbase][0], 16, 0, 0);
      __builtin_amdgcn_global_load_lds((const g_void*)(Bb + (size_t)(j * 64) * K + k0),
                                       (lds_void*)&Bs[d][j * 64 + wbase][0], 16, 0, 0);
    }
  };

  auto compute = [&](int d) {
    short8 aF[4], bF[4];
#pragma unroll
    for (int mi = 0; mi < 4; ++mi)
      aF[mi] = *(const short8*)&As[d][wr * 64 + mi * 16 + lr][kg * 8];
#pragma unroll
    for (int ni = 0; ni < 4; ++ni)
      bF[ni] = *(const short8*)&Bs[d][wc * 64 + ni * 16 + lr][kg * 8];
#pragma unroll
    for (int mi = 0; mi < 4; ++mi)
#pragma unroll
      for (int ni = 0; ni < 4; ++ni)
        acc[mi][ni] = __builtin_amdgcn_mfma_f32_16x16x32_bf16(
            aF[mi], bF[ni], acc[mi][ni], 0, 0, 0);
  };

  stage(0, 0);
  __syncthreads();
  int c = 0;
  const int NT = K >> 5;
  for (int t = 0; t < NT; ++t) {
    if (t + 1 < NT) stage(c ^ 1, (t + 1) << 5);
    compute(c);
    __syncthreads();
    c ^= 1;
  }

#pragma unroll
  for (int mi = 0; mi < 4; mi++) {
#pragma unroll
    for (int ni = 0; ni < 4; ni++) {
#pragma unroll
      for (int r = 0; r < 4; r++) {
        const int row = brow + wr * 64 + mi * 16 + kg * 4 + r;
        const int col = bcol + wc * 64 + ni * 16 + lr;
        float v = acc[mi][ni][r];
        if (col < 512) {                       // q
          v += qb[col];
          Qb[(size_t)row * 512 + col] = f2bf(v);
        } else if (col < 1024) {               // k
          const int c2 = col - 512;
          v += kb[c2];
          outK[(size_t)row * 512 + c2] = v;
          Kb[(size_t)row * 512 + c2] = f2bf(v);
        } else {                               // v
          const int c2 = col - 1024;
          v += vb[c2];
          outV[(size_t)row * 2048 + c2] = v;
          Vb[(size_t)row * 2048 + c2] = f2bf(v);
        }
      }
    }
  }
}

// ---------------------------------------------------------------------------
// 256^2 4-phase GEMM (r7-exact; scores GEMM, 2-D grid (16,16)).
// ---------------------------------------------------------------------------
__global__ __launch_bounds__(512, 2)
void gemm256_kernel(const unsigned short* __restrict__ A,
                    const unsigned short* __restrict__ B,
                    int M, int N, int K,
                    const float* __restrict__ bias,
                    const float* __restrict__ resid,
                    float scale, int relu,
                    float* __restrict__ outF,
                    unsigned short* __restrict__ outB)
{
  __shared__ __align__(16) unsigned short lds[2][2][2][128][64];  // 128 KiB

  const int tid  = threadIdx.x;
  const int lane = tid & 63;
  const int wave = tid >> 6;     // 0..7
  const int wm   = wave >> 2;    // 0..1
  const int wn   = wave & 3;     // 0..3
  const int lr   = lane & 15;
  const int kg   = lane >> 4;
  const int brow = blockIdx.x * 256;
  const int bcol = blockIdx.y * 256;

  const int srow = tid >> 3;                              // 0..63
  const int ssw  = ((tid & 7) * 8) ^ ((srow & 7) << 3);   // pre-swizzled k
  const unsigned short* Asrc = A + (size_t)(brow + srow) * K + ssw;
  const unsigned short* Bsrc = B + (size_t)(bcol + srow) * K + ssw;

  char* lbase = (char*)&lds[0][0][0][0][0];
  const int woff = wave * 1024;

  f32x4 acc[8][4];
#pragma unroll
  for (int i = 0; i < 8; ++i)
#pragma unroll
    for (int j = 0; j < 4; ++j) acc[i][j] = (f32x4){0.f, 0.f, 0.f, 0.f};

  const int NT = K >> 6;

  auto SA = [&](int d, int h, int q, int tl) {
    __builtin_amdgcn_global_load_lds(
        (const g_void*)(Asrc + (size_t)(h * 128 + q * 64) * K + tl * 64),
        (lds_void*)(lbase + d * 32768 + h * 16384 + q * 8192 + woff), 16, 0, 0);
  };
  auto SB = [&](int d, int h, int q, int tl) {
    __builtin_amdgcn_global_load_lds(
        (const g_void*)(Bsrc + (size_t)(h * 128 + q * 64) * K + tl * 64),
        (lds_void*)(lbase + 65536 + d * 32768 + h * 16384 + q * 8192 + woff), 16, 0, 0);
  };

  auto LDA = [&](short8* a, int d, int mh, int ks) {
    const char* reg = lbase + d * 32768 + wm * 16384;
    const int ke = (ks * 32 + kg * 8) ^ ((lr & 7) << 3);
#pragma unroll
    for (int i = 0; i < 4; ++i) {
      const int row = (mh * 4 + i) * 16 + lr;
      a[i] = *(const short8*)(reg + row * 128 + ke * 2);
    }
  };
  auto LDB = [&](short8* b, int d, int ks) {
    const char* reg = lbase + 65536 + d * 32768 + (wn >> 1) * 16384;
    const int ke = (ks * 32 + kg * 8) ^ ((lr & 7) << 3);
#pragma unroll
    for (int n = 0; n < 4; ++n) {
      const int row = (wn & 1) * 64 + n * 16 + lr;
      b[n] = *(const short8*)(reg + row * 128 + ke * 2);
    }
  };

  auto MM = [&](int mh, short8* a, short8* b) {
    __builtin_amdgcn_s_setprio(1);
#pragma unroll
    for (int i = 0; i < 4; ++i)
#pragma unroll
      for (int n = 0; n < 4; ++n)
        acc[mh * 4 + i][n] = __builtin_amdgcn_mfma_f32_16x16x32_bf16(
            a[i], b[n], acc[mh * 4 + i][n], 0, 0, 0);
    __builtin_amdgcn_s_setprio(0);
  };

  SA(0, 0, 0, 0); SA(0, 0, 1, 0); SA(0, 1, 0, 0); SA(0, 1, 1, 0);
  SB(0, 0, 0, 0); SB(0, 0, 1, 0); SB(0, 1, 0, 0); SB(0, 1, 1, 0);
  SB(1, 0, 0, 1); SB(1, 0, 1, 1); SA(1, 0, 0, 1);
  SB(1, 1, 0, 1); SB(1, 1, 1, 1); SA(1, 1, 0, 1);
  VMCNT6();
  BARRIER();

  short8 aT[4], bF0[4], bF1[4];
  for (int t = 0; t < NT; ++t) {
    const int buf = t & 1, nb = buf ^ 1;
    const int t1 = (t + 1 < NT) ? t + 1 : NT - 1;
    const int t2 = (t + 2 < NT) ? t + 2 : NT - 1;

    LDA(aT, buf, 0, 0); LDB(bF0, buf, 0);
    SA(nb, 0, 1, t1); SA(nb, 1, 1, t1);
    BARRIER(); MM(0, aT, bF0); BARRIER();

    LDA(aT, buf, 0, 1); LDB(bF1, buf, 1);
    BARRIER(); MM(0, aT, bF1); BARRIER();

    LDA(aT, buf, 1, 0);
    SB(buf, 0, 0, t2); SB(buf, 0, 1, t2); SA(buf, 0, 0, t2);
    BARRIER(); MM(1, aT, bF0); BARRIER();

    LDA(aT, buf, 1, 1);
    SB(buf, 1, 0, t2); SB(buf, 1, 1, t2); SA(buf, 1, 0, t2);
    BARRIER(); MM(1, aT, bF1);
    VMCNT6();
    BARRIER();
  }
  VMCNT0();

#pragma unroll
  for (int mi = 0; mi < 8; ++mi) {
#pragma unroll
    for (int ni = 0; ni < 4; ++ni) {
#pragma unroll
      for (int r = 0; r < 4; ++r) {
        const int row = brow + wm * 128 + mi * 16 + kg * 4 + r;
        const int col = bcol + wn * 64 + ni * 16 + lr;
        float v = acc[mi][ni][r] * scale;
        if (bias)  v += bias[col];
        if (resid) v += resid[(size_t)row * N + col];
        if (relu)  v = fmaxf(v, 0.0f);
        if (outF)  outF[(size_t)row * N + col] = v;
        if (outB)  outB[(size_t)row * N + col] = f2bf(v);
      }
    }
  }
}

// ---------------------------------------------------------------------------
// 256x128 reg-double-buffered GEMM (r7-exact, 2-buffer; FF1/FF2 control arm).
// ---------------------------------------------------------------------------
__global__ __launch_bounds__(512, 2)
void gemm256x128_kernel(const unsigned short* __restrict__ A,
                        const unsigned short* __restrict__ B,
                        int M, int N, int K,
                        const float* __restrict__ bias,
                        const float* __restrict__ resid,
                        float scale, int relu,
                        float* __restrict__ outF,
                        unsigned short* __restrict__ outB)
{
  __shared__ __align__(16) unsigned short lds[49152];   // 96 KiB

  const int tid  = threadIdx.x;
  const int lane = tid & 63;
  const int wave = tid >> 6;
  const int wm   = wave >> 1;
  const int wn   = wave & 1;
  const int lr   = lane & 15;
  const int kg   = lane >> 4;
  const int brow = blockIdx.x * 256;
  const int bcol = blockIdx.y * 128;

  const int srow = tid >> 3;
  const int ssw  = ((tid & 7) * 8) ^ ((srow & 7) << 3);
  const unsigned short* Asrc = A + (size_t)(brow + srow) * K + ssw;
  const unsigned short* Bsrc = B + (size_t)(bcol + srow) * K + ssw;

  char* lbase = (char*)&lds[0];
  const int woff = wave * 1024;

  f32x4 acc[4][4];
#pragma unroll
  for (int i = 0; i < 4; ++i)
#pragma unroll
    for (int j = 0; j < 4; ++j) acc[i][j] = (f32x4){0.f, 0.f, 0.f, 0.f};

  const int NT = K >> 6;

  auto STAGE = [&](int d, int tl) {
#pragma unroll
    for (int r = 0; r < 4; ++r)
      __builtin_amdgcn_global_load_lds(
          (const g_void*)(Asrc + (size_t)(r * 64) * K + tl * 64),
          (lds_void*)(lbase + d * 32768 + r * 8192 + woff), 16, 0, 0);
#pragma unroll
    for (int r = 0; r < 2; ++r)
      __builtin_amdgcn_global_load_lds(
          (const g_void*)(Bsrc + (size_t)(r * 64) * K + tl * 64),
          (lds_void*)(lbase + 65536 + d * 16384 + r * 8192 + woff), 16, 0, 0);
  };

  auto RD = [&](short8* a, short8* b, int d) {
#pragma unroll
    for (int ks = 0; ks < 2; ++ks) {
      const int ke = (ks * 32 + kg * 8) ^ ((lr & 7) << 3);
      const char* ra = lbase + d * 32768;
      const char* rb = lbase + 65536 + d * 16384;
#pragma unroll
      for (int mi = 0; mi < 4; ++mi)
        a[ks * 4 + mi] = *(const short8*)(ra + (wm * 64 + mi * 16 + lr) * 128 + ke * 2);
#pragma unroll
      for (int n = 0; n < 4; ++n)
        b[ks * 4 + n] = *(const short8*)(rb + (wn * 64 + n * 16 + lr) * 128 + ke * 2);
    }
  };

  auto MMALL = [&](short8* a, short8* b) {
    __builtin_amdgcn_s_setprio(1);
#pragma unroll
    for (int ks = 0; ks < 2; ++ks)
#pragma unroll
      for (int mi = 0; mi < 4; ++mi)
#pragma unroll
        for (int n = 0; n < 4; ++n)
          acc[mi][n] = __builtin_amdgcn_mfma_f32_16x16x32_bf16(
              a[ks * 4 + mi], b[ks * 4 + n], acc[mi][n], 0, 0, 0);
    __builtin_amdgcn_s_setprio(0);
  };

  STAGE(0, 0);
  STAGE(1, 1);
  VMCNT0();
  BARRIER();
  short8 aE[8], bE[8], aO[8], bO[8];
  RD(aE, bE, 0);
  LGKM0();

  for (int t = 0; t < NT; t += 2) {
    VMCNT0();
    BARRIER();
    { const int t2 = (t + 2 < NT) ? t + 2 : NT - 1; STAGE(0, t2); }
    RD(aO, bO, 1);
    MMALL(aE, bE);
    LGKM0();
    VMCNT0();
    BARRIER();
    { const int t3 = (t + 3 < NT) ? t + 3 : NT - 1; STAGE(1, t3); }
    RD(aE, bE, 0);
    MMALL(aO, bO);
    LGKM0();
  }
  VMCNT0();

#pragma unroll
  for (int mi = 0; mi < 4; ++mi) {
#pragma unroll
    for (int ni = 0; ni < 4; ++ni) {
#pragma unroll
      for (int r = 0; r < 4; ++r) {
        const int row = brow + wm * 64 + mi * 16 + kg * 4 + r;
        const int col = bcol + wn * 64 + ni * 16 + lr;
        float v = acc[mi][ni][r] * scale;
        if (bias)  v += bias[col];
        if (resid) v += resid[(size_t)row * N + col];
        if (relu)  v = fmaxf(v, 0.0f);
        if (outF)  outF[(size_t)row * N + col] = v;
        if (outB)  outB[(size_t)row * N + col] = f2bf(v);
      }
    }
  }
}

// ---------------------------------------------------------------------------
// 256x128 3-buffer counted-vmcnt GEMM (r8 pipeline WITHOUT the XCD swizzle;
// P-V test arm).  LDS: A[3][256][64] 96K + B[3][128][64] 48K = 144 KiB.
// Per sub-iter: VMCNT6 (drain oldest 6 = t+1; t+2 stays in flight) ->
// BARRIER -> STAGE(t+3 -> buf t%3) -> RD(t+1) -> MMALL(t) -> LGKM0.
// ---------------------------------------------------------------------------
__global__ __launch_bounds__(512, 2)
void gemm256x128_k3_kernel(const unsigned short* __restrict__ A,
                           const unsigned short* __restrict__ B,
                           int M, int N, int K,
                           const float* __restrict__ bias,
                           const float* __restrict__ resid,
                           float scale, int relu,
                           float* __restrict__ outF,
                           unsigned short* __restrict__ outB)
{
  __shared__ __align__(16) unsigned short lds[73728];   // 144 KiB

  const int tid  = threadIdx.x;
  const int lane = tid & 63;
  const int wave = tid >> 6;
  const int wm   = wave >> 1;
  const int wn   = wave & 1;
  const int lr   = lane & 15;
  const int kg   = lane >> 4;
  const int brow = blockIdx.x * 256;
  const int bcol = blockIdx.y * 128;

  const int srow = tid >> 3;
  const int ssw  = ((tid & 7) * 8) ^ ((srow & 7) << 3);
  const unsigned short* Asrc = A + (size_t)(brow + srow) * K + ssw;
  const unsigned short* Bsrc = B + (size_t)(bcol + srow) * K + ssw;

  char* lbase = (char*)&lds[0];
  const int woff = wave * 1024;

  f32x4 acc[4][4];
#pragma unroll
  for (int i = 0; i < 4; ++i)
#pragma unroll
    for (int j = 0; j < 4; ++j) acc[i][j] = (f32x4){0.f, 0.f, 0.f, 0.f};

  const int NT = K >> 6;

  auto STAGE = [&](int d, int tl) {
#pragma unroll
    for (int r = 0; r < 4; ++r)
      __builtin_amdgcn_global_load_lds(
          (const g_void*)(Asrc + (size_t)(r * 64) * K + tl * 64),
          (lds_void*)(lbase + d * 32768 + r * 8192 + woff), 16, 0, 0);
#pragma unroll
    for (int r = 0; r < 2; ++r)
      __builtin_amdgcn_global_load_lds(
          (const g_void*)(Bsrc + (size_t)(r * 64) * K + tl * 64),
          (lds_void*)(lbase + 98304 + d * 16384 + r * 8192 + woff), 16, 0, 0);
  };

  auto RD = [&](short8* a, short8* b, int d) {
#pragma unroll
    for (int ks = 0; ks < 2; ++ks) {
      const int ke = (ks * 32 + kg * 8) ^ ((lr & 7) << 3);
      const char* ra = lbase + d * 32768;
      const char* rb = lbase + 98304 + d * 16384;
#pragma unroll
      for (int mi = 0; mi < 4; ++mi)
        a[ks * 4 + mi] = *(const short8*)(ra + (wm * 64 + mi * 16 + lr) * 128 + ke * 2);
#pragma unroll
      for (int n = 0; n < 4; ++n)
        b[ks * 4 + n] = *(const short8*)(rb + (wn * 64 + n * 16 + lr) * 128 + ke * 2);
    }
  };

  auto MMALL = [&](short8* a, short8* b) {
    __builtin_amdgcn_s_setprio(1);
#pragma unroll
    for (int ks = 0; ks < 2; ++ks)
#pragma unroll
      for (int mi = 0; mi < 4; ++mi)
#pragma unroll
        for (int n = 0; n < 4; ++n)
          acc[mi][n] = __builtin_amdgcn_mfma_f32_16x16x32_bf16(
              a[ks * 4 + mi], b[ks * 4 + n], acc[mi][n], 0, 0, 0);
    __builtin_amdgcn_s_setprio(0);
  };

  // prologue: tiles 0,1,2 -> bufs 0,1,2; drain tile 0 (12 stay in flight)
  STAGE(0, 0);
  STAGE(1, 1);
  STAGE(2, 2);
  VMCNT12();
  BARRIER();
  short8 aE[8], bE[8], aO[8], bO[8];
  RD(aE, bE, 0);
  LGKM0();

  for (int t = 0; t < NT; t += 2) {
    VMCNT6();
    BARRIER();
    STAGE(t % 3, (t + 3 < NT) ? t + 3 : NT - 1);
    RD(aO, bO, (t + 1) % 3);
    MMALL(aE, bE);
    LGKM0();
    VMCNT6();
    BARRIER();
    STAGE((t + 1) % 3, (t + 4 < NT) ? t + 4 : NT - 1);
    RD(aE, bE, (t + 2) % 3);
    MMALL(aO, bO);
    LGKM0();
  }
  VMCNT0();

#pragma unroll
  for (int mi = 0; mi < 4; ++mi) {
#pragma unroll
    for (int ni = 0; ni < 4; ++ni) {
#pragma unroll
      for (int r = 0; r < 4; ++r) {
        const int row = brow + wm * 64 + mi * 16 + kg * 4 + r;
        const int col = bcol + wn * 64 + ni * 16 + lr;
        float v = acc[mi][ni][r] * scale;
        if (bias)  v += bias[col];
        if (resid) v += resid[(size_t)row * N + col];
        if (relu)  v = fmaxf(v, 0.0f);
        if (outF)  outF[(size_t)row * N + col] = v;
        if (outB)  outB[(size_t)row * N + col] = f2bf(v);
      }
    }
  }
}

// ---------------------------------------------------------------------------
// register-resident row softmax over bf16 scores: 16 elems/thread in regs.
// ---------------------------------------------------------------------------
__global__ __launch_bounds__(256) void softmax_kernel(
    const unsigned short* __restrict__ Scb, unsigned short* __restrict__ P) {
  __shared__ float redm[4];
  __shared__ float reds[4];
  const int tid = threadIdx.x;
  const int row = blockIdx.x;
  const unsigned short* src = Scb + (size_t)row * SEQ;

  short8 h0 = *(const short8*)(src + tid * 8);
  short8 h1 = *(const short8*)(src + tid * 8 + 2048);
  float f[16];
#pragma unroll
  for (int i = 0; i < 8; ++i) f[i]     = bf2f((unsigned short)h0[i]);
#pragma unroll
  for (int i = 0; i < 8; ++i) f[8 + i] = bf2f((unsigned short)h1[i]);

  float lmax = f[0];
#pragma unroll
  for (int i = 1; i < 16; ++i) lmax = fmaxf(lmax, f[i]);
#pragma unroll
  for (int off = 32; off > 0; off >>= 1)
    lmax = fmaxf(lmax, __shfl_xor(lmax, off, 64));
  if ((tid & 63) == 0) redm[tid >> 6] = lmax;
  __syncthreads();
  const float m = fmaxf(fmaxf(redm[0], redm[1]), fmaxf(redm[2], redm[3]));

  float lsum = 0.0f;
#pragma unroll
  for (int i = 0; i < 16; ++i) { f[i] = __expf(f[i] - m); lsum += f[i]; }
#pragma unroll
  for (int off = 32; off > 0; off >>= 1)
    lsum += __shfl_xor(lsum, off, 64);
  if ((tid & 63) == 0) reds[tid >> 6] = lsum;
  __syncthreads();
  const float inv = 1.0f / (reds[0] + reds[1] + reds[2] + reds[3]);

  unsigned short* dst = P + (size_t)row * SEQ;
  short8 o0, o1;
#pragma unroll
  for (int i = 0; i < 8; ++i) o0[i] = (short)f2bf(f[i] * inv);
#pragma unroll
  for (int i = 0; i < 8; ++i) o1[i] = (short)f2bf(f[8 + i] * inv);
  *(short8*)(dst + tid * 8)        = o0;
  *(short8*)(dst + tid * 8 + 2048) = o1;
}

// ---------------------------------------------------------------------------
// launch
// ---------------------------------------------------------------------------
extern "C" void kernel_launch(void* const* d_in, const int* in_sizes, int n_in,
                              void* d_out, int out_size, void* d_ws, size_t ws_size,
                              hipStream_t stream) {
  const float* x  = (const float*)d_in[0];
  const float* qw = (const float*)d_in[1];
  const float* qb = (const float*)d_in[2];
  const float* kw = (const float*)d_in[3];
  const float* kb = (const float*)d_in[4];
  const float* vw = (const float*)d_in[5];
  const float* vb = (const float*)d_in[6];
  const float* w1 = (const float*)d_in[7];
  const float* b1 = (const float*)d_in[8];
  const float* w2 = (const float*)d_in[9];
  const float* b2 = (const float*)d_in[10];
  float* out = (float*)d_out;   // [hidden(8388608) | k(2097152) | v(8388608)]
  char* ws = (char*)d_ws;

  const size_t MB = 1048576;
  unsigned short* Xb    = (unsigned short*)(ws + 0 * MB);    // 16M, dead after QKV
  unsigned short* QKVWb = (unsigned short*)(ws + 16 * MB);   // 12M, dead after QKV
  unsigned short* Pb    = (unsigned short*)(ws + 0 * MB);    // 32M, overlays Xb+QKVWb
  unsigned short* W1b   = (unsigned short*)(ws + 32 * MB);   //  8M
  unsigned short* W2b   = (unsigned short*)(ws + 40 * MB);   //  8M
  unsigned short* Qb    = (unsigned short*)(ws + 48 * MB);   //  4M
  unsigned short* Kb    = (unsigned short*)(ws + 52 * MB);   //  4M
  unsigned short* Vb    = (unsigned short*)(ws + 56 * MB);   // 16M, dead after transpose
  unsigned short* VTb   = (unsigned short*)(ws + 72 * MB);   // 16M
  unsigned short* Scb   = (unsigned short*)(ws + 88 * MB);   // 32M bf16 scores, dead after softmax
  float*          XR    = (float*)(ws + 88 * MB);            // 32M overlays dead Scb
  unsigned short* X1b   = (unsigned short*)(ws + 120 * MB);  // 16M
  unsigned short* XRb   = (unsigned short*)(ws + 136 * MB);  // 16M

  // casts to bf16 (QKVWb = [qw ; kw ; vw] rows concatenated)
  cast_bf16_kernel<<<8192, 256, 0, stream>>>(x,  Xb, 2097152);
  cast_bf16_kernel<<<1024, 256, 0, stream>>>(qw, QKVWb, 262144);
  cast_bf16_kernel<<<1024, 256, 0, stream>>>(kw, QKVWb + 512 * 2048, 262144);
  cast_bf16_kernel<<<4096, 256, 0, stream>>>(vw, QKVWb + 1024 * 2048, 1048576);
  cast_bf16_kernel<<<4096, 256, 0, stream>>>(w1, W1b, 1048576);
  cast_bf16_kernel<<<4096, 256, 0, stream>>>(w2, W2b, 1048576);

  // q,k,v = x @ [qw;kw;vw]^T + bias   (768 blocks, 3 blk/CU)
  gemm_qkv_kernel<<<dim3(32, 24), dim3(256), 0, stream>>>(
      Xb, QKVWb, SEQ, 3072, DMODEL, qb, kb, vb,
      out + 8388608, out + 10485760, Qb, Kb, Vb);
  // VTb = Vb^T  ([2048][4096])
  transpose_bf16_kernel<<<dim3(64, 32), dim3(256), 0, stream>>>(Vb, VTb, SEQ, DMODEL);
  // scores = (q @ k^T) / sqrt(512)  -> bf16 (halved round-trip)
  gemm256_kernel<<<dim3(16, 16), dim3(512), 0, stream>>>(
      Qb, Kb, SEQ, SEQ, DINT, nullptr, nullptr,
      0.04419417382415922f, 0, nullptr, Scb);
  // P = softmax(scores)  -> bf16
  softmax_kernel<<<4096, dim3(256), 0, stream>>>(Scb, Pb);
  // x_residual = P @ V + x  -> fp32 + bf16   [3-buffer test arm]
  gemm256x128_k3_kernel<<<dim3(16, 16), dim3(512), 0, stream>>>(
      Pb, VTb, SEQ, DMODEL, SEQ, nullptr, x, 1.0f, 0, XR, XRb);
  // x1 = relu(x_residual @ w1^T + b1)  -> bf16   [2-buffer control arm]
  gemm256x128_kernel<<<dim3(16, 16), dim3(512), 0, stream>>>(
      XRb, W1b, SEQ, DMODEL, DMODEL, b1, nullptr, 1.0f, 1, nullptr, X1b);
  // hidden = x1 @ w2^T + b2 + x_residual  -> fp32 (out)
  gemm256x128_kernel<<<dim3(16, 16), dim3(512), 0, stream>>>(
      X1b, W2b, SEQ, DMODEL, DMODEL, b2, XR, 1.0f, 0, out, nullptr);
}

// Round 13
// 325.466 us; speedup vs baseline: 1.7255x; 1.0621x over previous
//
#include <hip/hip_runtime.h>
#include <cstdint>
#include <cstddef>

// ---------------------------------------------------------------------------
// TransformerLayer: hidden,k,v = f(x, qw,qb, kw,kb, vw,vb, w1,b1, w2,b2)
// S=4096, D_MODEL=2048, D_INT=512.  bf16 MFMA GEMMs, fp32 accumulate.
// Round 13: consolidation.  (1) V^T written directly from QKV epilogue
// (transpose kernel deleted), (2) one fused cast kernel, (3) FF1/FF2/P-V
// all on the k3 3-buffer pipeline (measured >= 2-buffer in r12 A/B).
// ---------------------------------------------------------------------------

typedef __attribute__((ext_vector_type(8))) short short8;   // 8 x bf16 bits
typedef __attribute__((ext_vector_type(4))) float f32x4;    // MFMA accum

typedef __attribute__((address_space(3))) void lds_void;
typedef __attribute__((address_space(1))) void g_void;

#define SEQ    4096
#define DMODEL 2048
#define DINT   512

#define MEMF() asm volatile("" ::: "memory")
#define BARRIER() do { MEMF(); __builtin_amdgcn_s_barrier(); MEMF(); } while (0)
#define VMCNT12() asm volatile("s_waitcnt vmcnt(12)" ::: "memory")
#define VMCNT6() asm volatile("s_waitcnt vmcnt(6)" ::: "memory")
#define VMCNT0() asm volatile("s_waitcnt vmcnt(0)" ::: "memory")
#define LGKM0()  asm volatile("s_waitcnt lgkmcnt(0)" ::: "memory")

// fp32 -> bf16 bits, round-to-nearest-even
__device__ __forceinline__ unsigned short f2bf(float f) {
  union { float f; unsigned int u; } a;
  a.f = f;
  unsigned int u = a.u;
  u += 0x7fffu + ((u >> 16) & 1u);
  return (unsigned short)(u >> 16);
}
__device__ __forceinline__ float bf2f(unsigned short u) {
  union { unsigned int i; float f; } a;
  a.i = ((unsigned int)u) << 16;
  return a.f;
}

// ---------------------------------------------------------------------------
// fused cast: all six fp32 tensors -> bf16 in one launch (region lookup).
// float4-unit boundaries: x 2097152 | qw 262144 | kw 262144 | vw 1048576 |
// w1 1048576 | w2 1048576  (total 5767168; grid 22528 x 256, exact).
// ---------------------------------------------------------------------------
__global__ __launch_bounds__(256) void cast_all_kernel(
    const float* __restrict__ x,  const float* __restrict__ qw,
    const float* __restrict__ kw, const float* __restrict__ vw,
    const float* __restrict__ w1, const float* __restrict__ w2,
    unsigned short* __restrict__ Xb, unsigned short* __restrict__ QKVWb,
    unsigned short* __restrict__ W1b, unsigned short* __restrict__ W2b) {
  const int i = blockIdx.x * 256 + threadIdx.x;
  const float* src; unsigned short* dst; int off;
  if (i < 2097152)      { src = x;  dst = Xb;               off = i; }
  else if (i < 2359296) { src = qw; dst = QKVWb;            off = i - 2097152; }
  else if (i < 2621440) { src = kw; dst = QKVWb + 1048576;  off = i - 2359296; }
  else if (i < 3670016) { src = vw; dst = QKVWb + 2097152;  off = i - 2621440; }
  else if (i < 4718592) { src = w1; dst = W1b;              off = i - 3670016; }
  else                  { src = w2; dst = W2b;              off = i - 4718592; }
  float4 v = ((const float4*)src)[off];
  ushort4 o;
  o.x = f2bf(v.x); o.y = f2bf(v.y); o.z = f2bf(v.z); o.w = f2bf(v.w);
  ((ushort4*)dst)[off] = o;
}

// ---------------------------------------------------------------------------
// Fused QKV GEMM: 2-phase 128^2, BK=32 double-buffered (32 KiB LDS,
// grid (32,24)=768 -> 3 blk/CU).  Epilogue writes V^T directly (ushort4 of
// 4 consecutive rows at fixed col -> VTb[c2*4096+row0], 8B aligned).
// ---------------------------------------------------------------------------
__global__ __launch_bounds__(256)
void gemm_qkv_kernel(const unsigned short* __restrict__ A,
                     const unsigned short* __restrict__ W,
                     int M, int N, int K,
                     const float* __restrict__ qb,
                     const float* __restrict__ kb,
                     const float* __restrict__ vb,
                     float* __restrict__ outK,
                     float* __restrict__ outV,
                     unsigned short* __restrict__ Qb,
                     unsigned short* __restrict__ Kb,
                     unsigned short* __restrict__ VTb)
{
  __shared__ __align__(16) unsigned short As[2][128][32];   // 2 x 8 KiB
  __shared__ __align__(16) unsigned short Bs[2][128][32];   // 2 x 8 KiB

  const int tid  = threadIdx.x;
  const int lane = tid & 63;
  const int wave = tid >> 6;
  const int wr   = wave >> 1;
  const int wc   = wave & 1;
  const int brow = blockIdx.x * 128;
  const int bcol = blockIdx.y * 128;
  const int lr   = lane & 15;
  const int kg   = lane >> 4;

  const int srow  = tid >> 2;          // 0..63
  const int scol  = (tid & 3) * 8;
  const int wbase = wave * 16;
  const unsigned short* Ab = A + (size_t)(brow + srow) * K + scol;
  const unsigned short* Bb = W + (size_t)(bcol + srow) * K + scol;

  f32x4 acc[4][4];
#pragma unroll
  for (int i = 0; i < 4; i++)
#pragma unroll
    for (int j = 0; j < 4; j++) acc[i][j] = (f32x4){0.f, 0.f, 0.f, 0.f};

  auto stage = [&](int d, int k0) {
#pragma unroll
    for (int j = 0; j < 2; ++j) {
      __builtin_amdgcn_global_load_lds((const g_void*)(Ab + (size_t)(j * 64) * K + k0),
                                       (lds_void*)&As[d][j * 64 + wbase][0], 16, 0, 0);
      __builtin_amdgcn_global_load_lds((const g_void*)(Bb + (size_t)(j * 64) * K + k0),
                                       (lds_void*)&Bs[d][j * 64 + wbase][0], 16, 0, 0);
    }
  };

  auto compute = [&](int d) {
    short8 aF[4], bF[4];
#pragma unroll
    for (int mi = 0; mi < 4; ++mi)
      aF[mi] = *(const short8*)&As[d][wr * 64 + mi * 16 + lr][kg * 8];
#pragma unroll
    for (int ni = 0; ni < 4; ++ni)
      bF[ni] = *(const short8*)&Bs[d][wc * 64 + ni * 16 + lr][kg * 8];
#pragma unroll
    for (int mi = 0; mi < 4; ++mi)
#pragma unroll
      for (int ni = 0; ni < 4; ++ni)
        acc[mi][ni] = __builtin_amdgcn_mfma_f32_16x16x32_bf16(
            aF[mi], bF[ni], acc[mi][ni], 0, 0, 0);
  };

  stage(0, 0);
  __syncthreads();
  int c = 0;
  const int NT = K >> 5;
  for (int t = 0; t < NT; ++t) {
    if (t + 1 < NT) stage(c ^ 1, (t + 1) << 5);
    compute(c);
    __syncthreads();
    c ^= 1;
  }

#pragma unroll
  for (int mi = 0; mi < 4; mi++) {
#pragma unroll
    for (int ni = 0; ni < 4; ni++) {
      const int row0 = brow + wr * 64 + mi * 16 + kg * 4;
      const int col  = bcol + wc * 64 + ni * 16 + lr;
      if (col < 512) {                       // q -> Qb bf16
        const float b = qb[col];
#pragma unroll
        for (int r = 0; r < 4; r++)
          Qb[(size_t)(row0 + r) * 512 + col] = f2bf(acc[mi][ni][r] + b);
      } else if (col < 1024) {               // k -> outK fp32 + Kb bf16
        const int c2 = col - 512;
        const float b = kb[c2];
#pragma unroll
        for (int r = 0; r < 4; r++) {
          const float t = acc[mi][ni][r] + b;
          outK[(size_t)(row0 + r) * 512 + c2] = t;
          Kb[(size_t)(row0 + r) * 512 + c2] = f2bf(t);
        }
      } else {                               // v -> outV fp32 + VTb bf16 (transposed)
        const int c2 = col - 1024;
        const float b = vb[c2];
        ushort4 o;
#pragma unroll
        for (int r = 0; r < 4; r++) {
          const float t = acc[mi][ni][r] + b;
          outV[(size_t)(row0 + r) * 2048 + c2] = t;
          ((unsigned short*)&o)[r] = f2bf(t);
        }
        *(ushort4*)(&VTb[(size_t)c2 * 4096 + row0]) = o;
      }
    }
  }
}

// ---------------------------------------------------------------------------
// 256^2 4-phase GEMM (r7-exact; scores GEMM, 2-D grid (16,16)).
// ---------------------------------------------------------------------------
__global__ __launch_bounds__(512, 2)
void gemm256_kernel(const unsigned short* __restrict__ A,
                    const unsigned short* __restrict__ B,
                    int M, int N, int K,
                    const float* __restrict__ bias,
                    const float* __restrict__ resid,
                    float scale, int relu,
                    float* __restrict__ outF,
                    unsigned short* __restrict__ outB)
{
  __shared__ __align__(16) unsigned short lds[2][2][2][128][64];  // 128 KiB

  const int tid  = threadIdx.x;
  const int lane = tid & 63;
  const int wave = tid >> 6;     // 0..7
  const int wm   = wave >> 2;    // 0..1
  const int wn   = wave & 3;     // 0..3
  const int lr   = lane & 15;
  const int kg   = lane >> 4;
  const int brow = blockIdx.x * 256;
  const int bcol = blockIdx.y * 256;

  const int srow = tid >> 3;                              // 0..63
  const int ssw  = ((tid & 7) * 8) ^ ((srow & 7) << 3);   // pre-swizzled k
  const unsigned short* Asrc = A + (size_t)(brow + srow) * K + ssw;
  const unsigned short* Bsrc = B + (size_t)(bcol + srow) * K + ssw;

  char* lbase = (char*)&lds[0][0][0][0][0];
  const int woff = wave * 1024;

  f32x4 acc[8][4];
#pragma unroll
  for (int i = 0; i < 8; ++i)
#pragma unroll
    for (int j = 0; j < 4; ++j) acc[i][j] = (f32x4){0.f, 0.f, 0.f, 0.f};

  const int NT = K >> 6;

  auto SA = [&](int d, int h, int q, int tl) {
    __builtin_amdgcn_global_load_lds(
        (const g_void*)(Asrc + (size_t)(h * 128 + q * 64) * K + tl * 64),
        (lds_void*)(lbase + d * 32768 + h * 16384 + q * 8192 + woff), 16, 0, 0);
  };
  auto SB = [&](int d, int h, int q, int tl) {
    __builtin_amdgcn_global_load_lds(
        (const g_void*)(Bsrc + (size_t)(h * 128 + q * 64) * K + tl * 64),
        (lds_void*)(lbase + 65536 + d * 32768 + h * 16384 + q * 8192 + woff), 16, 0, 0);
  };

  auto LDA = [&](short8* a, int d, int mh, int ks) {
    const char* reg = lbase + d * 32768 + wm * 16384;
    const int ke = (ks * 32 + kg * 8) ^ ((lr & 7) << 3);
#pragma unroll
    for (int i = 0; i < 4; ++i) {
      const int row = (mh * 4 + i) * 16 + lr;
      a[i] = *(const short8*)(reg + row * 128 + ke * 2);
    }
  };
  auto LDB = [&](short8* b, int d, int ks) {
    const char* reg = lbase + 65536 + d * 32768 + (wn >> 1) * 16384;
    const int ke = (ks * 32 + kg * 8) ^ ((lr & 7) << 3);
#pragma unroll
    for (int n = 0; n < 4; ++n) {
      const int row = (wn & 1) * 64 + n * 16 + lr;
      b[n] = *(const short8*)(reg + row * 128 + ke * 2);
    }
  };

  auto MM = [&](int mh, short8* a, short8* b) {
    __builtin_amdgcn_s_setprio(1);
#pragma unroll
    for (int i = 0; i < 4; ++i)
#pragma unroll
      for (int n = 0; n < 4; ++n)
        acc[mh * 4 + i][n] = __builtin_amdgcn_mfma_f32_16x16x32_bf16(
            a[i], b[n], acc[mh * 4 + i][n], 0, 0, 0);
    __builtin_amdgcn_s_setprio(0);
  };

  SA(0, 0, 0, 0); SA(0, 0, 1, 0); SA(0, 1, 0, 0); SA(0, 1, 1, 0);
  SB(0, 0, 0, 0); SB(0, 0, 1, 0); SB(0, 1, 0, 0); SB(0, 1, 1, 0);
  SB(1, 0, 0, 1); SB(1, 0, 1, 1); SA(1, 0, 0, 1);
  SB(1, 1, 0, 1); SB(1, 1, 1, 1); SA(1, 1, 0, 1);
  VMCNT6();
  BARRIER();

  short8 aT[4], bF0[4], bF1[4];
  for (int t = 0; t < NT; ++t) {
    const int buf = t & 1, nb = buf ^ 1;
    const int t1 = (t + 1 < NT) ? t + 1 : NT - 1;
    const int t2 = (t + 2 < NT) ? t + 2 : NT - 1;

    LDA(aT, buf, 0, 0); LDB(bF0, buf, 0);
    SA(nb, 0, 1, t1); SA(nb, 1, 1, t1);
    BARRIER(); MM(0, aT, bF0); BARRIER();

    LDA(aT, buf, 0, 1); LDB(bF1, buf, 1);
    BARRIER(); MM(0, aT, bF1); BARRIER();

    LDA(aT, buf, 1, 0);
    SB(buf, 0, 0, t2); SB(buf, 0, 1, t2); SA(buf, 0, 0, t2);
    BARRIER(); MM(1, aT, bF0); BARRIER();

    LDA(aT, buf, 1, 1);
    SB(buf, 1, 0, t2); SB(buf, 1, 1, t2); SA(buf, 1, 0, t2);
    BARRIER(); MM(1, aT, bF1);
    VMCNT6();
    BARRIER();
  }
  VMCNT0();

#pragma unroll
  for (int mi = 0; mi < 8; ++mi) {
#pragma unroll
    for (int ni = 0; ni < 4; ++ni) {
#pragma unroll
      for (int r = 0; r < 4; ++r) {
        const int row = brow + wm * 128 + mi * 16 + kg * 4 + r;
        const int col = bcol + wn * 64 + ni * 16 + lr;
        float v = acc[mi][ni][r] * scale;
        if (bias)  v += bias[col];
        if (resid) v += resid[(size_t)row * N + col];
        if (relu)  v = fmaxf(v, 0.0f);
        if (outF)  outF[(size_t)row * N + col] = v;
        if (outB)  outB[(size_t)row * N + col] = f2bf(v);
      }
    }
  }
}

// ---------------------------------------------------------------------------
// 256x128 3-buffer counted-vmcnt GEMM (P-V, FF1, FF2).  144 KiB LDS.
// Per sub-iter: VMCNT6 (drain oldest 6 = tile t+1; t+2 stays in flight) ->
// BARRIER -> STAGE(t+3 -> buf t%3) -> RD(t+1) -> MMALL(t) -> LGKM0.
// ---------------------------------------------------------------------------
__global__ __launch_bounds__(512, 2)
void gemm256x128_k3_kernel(const unsigned short* __restrict__ A,
                           const unsigned short* __restrict__ B,
                           int M, int N, int K,
                           const float* __restrict__ bias,
                           const float* __restrict__ resid,
                           float scale, int relu,
                           float* __restrict__ outF,
                           unsigned short* __restrict__ outB)
{
  __shared__ __align__(16) unsigned short lds[73728];   // 144 KiB

  const int tid  = threadIdx.x;
  const int lane = tid & 63;
  const int wave = tid >> 6;
  const int wm   = wave >> 1;
  const int wn   = wave & 1;
  const int lr   = lane & 15;
  const int kg   = lane >> 4;
  const int brow = blockIdx.x * 256;
  const int bcol = blockIdx.y * 128;

  const int srow = tid >> 3;
  const int ssw  = ((tid & 7) * 8) ^ ((srow & 7) << 3);
  const unsigned short* Asrc = A + (size_t)(brow + srow) * K + ssw;
  const unsigned short* Bsrc = B + (size_t)(bcol + srow) * K + ssw;

  char* lbase = (char*)&lds[0];
  const int woff = wave * 1024;

  f32x4 acc[4][4];
#pragma unroll
  for (int i = 0; i < 4; ++i)
#pragma unroll
    for (int j = 0; j < 4; ++j) acc[i][j] = (f32x4){0.f, 0.f, 0.f, 0.f};

  const int NT = K >> 6;   // even, >= 4 at all call sites (K = 2048 / 4096)

  auto STAGE = [&](int d, int tl) {
#pragma unroll
    for (int r = 0; r < 4; ++r)
      __builtin_amdgcn_global_load_lds(
          (const g_void*)(Asrc + (size_t)(r * 64) * K + tl * 64),
          (lds_void*)(lbase + d * 32768 + r * 8192 + woff), 16, 0, 0);
#pragma unroll
    for (int r = 0; r < 2; ++r)
      __builtin_amdgcn_global_load_lds(
          (const g_void*)(Bsrc + (size_t)(r * 64) * K + tl * 64),
          (lds_void*)(lbase + 98304 + d * 16384 + r * 8192 + woff), 16, 0, 0);
  };

  auto RD = [&](short8* a, short8* b, int d) {
#pragma unroll
    for (int ks = 0; ks < 2; ++ks) {
      const int ke = (ks * 32 + kg * 8) ^ ((lr & 7) << 3);
      const char* ra = lbase + d * 32768;
      const char* rb = lbase + 98304 + d * 16384;
#pragma unroll
      for (int mi = 0; mi < 4; ++mi)
        a[ks * 4 + mi] = *(const short8*)(ra + (wm * 64 + mi * 16 + lr) * 128 + ke * 2);
#pragma unroll
      for (int n = 0; n < 4; ++n)
        b[ks * 4 + n] = *(const short8*)(rb + (wn * 64 + n * 16 + lr) * 128 + ke * 2);
    }
  };

  auto MMALL = [&](short8* a, short8* b) {
    __builtin_amdgcn_s_setprio(1);
#pragma unroll
    for (int ks = 0; ks < 2; ++ks)
#pragma unroll
      for (int mi = 0; mi < 4; ++mi)
#pragma unroll
        for (int n = 0; n < 4; ++n)
          acc[mi][n] = __builtin_amdgcn_mfma_f32_16x16x32_bf16(
              a[ks * 4 + mi], b[ks * 4 + n], acc[mi][n], 0, 0, 0);
    __builtin_amdgcn_s_setprio(0);
  };

  // prologue: tiles 0,1,2 -> bufs 0,1,2; drain tile 0 (12 stay in flight)
  STAGE(0, 0);
  STAGE(1, 1);
  STAGE(2, 2);
  VMCNT12();
  BARRIER();
  short8 aE[8], bE[8], aO[8], bO[8];
  RD(aE, bE, 0);
  LGKM0();

  for (int t = 0; t < NT; t += 2) {
    VMCNT6();
    BARRIER();
    STAGE(t % 3, (t + 3 < NT) ? t + 3 : NT - 1);
    RD(aO, bO, (t + 1) % 3);
    MMALL(aE, bE);
    LGKM0();
    VMCNT6();
    BARRIER();
    STAGE((t + 1) % 3, (t + 4 < NT) ? t + 4 : NT - 1);
    RD(aE, bE, (t + 2) % 3);
    MMALL(aO, bO);
    LGKM0();
  }
  VMCNT0();

#pragma unroll
  for (int mi = 0; mi < 4; ++mi) {
#pragma unroll
    for (int ni = 0; ni < 4; ++ni) {
#pragma unroll
      for (int r = 0; r < 4; ++r) {
        const int row = brow + wm * 64 + mi * 16 + kg * 4 + r;
        const int col = bcol + wn * 64 + ni * 16 + lr;
        float v = acc[mi][ni][r] * scale;
        if (bias)  v += bias[col];
        if (resid) v += resid[(size_t)row * N + col];
        if (relu)  v = fmaxf(v, 0.0f);
        if (outF)  outF[(size_t)row * N + col] = v;
        if (outB)  outB[(size_t)row * N + col] = f2bf(v);
      }
    }
  }
}

// ---------------------------------------------------------------------------
// register-resident row softmax over bf16 scores: 16 elems/thread in regs.
// ---------------------------------------------------------------------------
__global__ __launch_bounds__(256) void softmax_kernel(
    const unsigned short* __restrict__ Scb, unsigned short* __restrict__ P) {
  __shared__ float redm[4];
  __shared__ float reds[4];
  const int tid = threadIdx.x;
  const int row = blockIdx.x;
  const unsigned short* src = Scb + (size_t)row * SEQ;

  short8 h0 = *(const short8*)(src + tid * 8);
  short8 h1 = *(const short8*)(src + tid * 8 + 2048);
  float f[16];
#pragma unroll
  for (int i = 0; i < 8; ++i) f[i]     = bf2f((unsigned short)h0[i]);
#pragma unroll
  for (int i = 0; i < 8; ++i) f[8 + i] = bf2f((unsigned short)h1[i]);

  float lmax = f[0];
#pragma unroll
  for (int i = 1; i < 16; ++i) lmax = fmaxf(lmax, f[i]);
#pragma unroll
  for (int off = 32; off > 0; off >>= 1)
    lmax = fmaxf(lmax, __shfl_xor(lmax, off, 64));
  if ((tid & 63) == 0) redm[tid >> 6] = lmax;
  __syncthreads();
  const float m = fmaxf(fmaxf(redm[0], redm[1]), fmaxf(redm[2], redm[3]));

  float lsum = 0.0f;
#pragma unroll
  for (int i = 0; i < 16; ++i) { f[i] = __expf(f[i] - m); lsum += f[i]; }
#pragma unroll
  for (int off = 32; off > 0; off >>= 1)
    lsum += __shfl_xor(lsum, off, 64);
  if ((tid & 63) == 0) reds[tid >> 6] = lsum;
  __syncthreads();
  const float inv = 1.0f / (reds[0] + reds[1] + reds[2] + reds[3]);

  unsigned short* dst = P + (size_t)row * SEQ;
  short8 o0, o1;
#pragma unroll
  for (int i = 0; i < 8; ++i) o0[i] = (short)f2bf(f[i] * inv);
#pragma unroll
  for (int i = 0; i < 8; ++i) o1[i] = (short)f2bf(f[8 + i] * inv);
  *(short8*)(dst + tid * 8)        = o0;
  *(short8*)(dst + tid * 8 + 2048) = o1;
}

// ---------------------------------------------------------------------------
// launch
// ---------------------------------------------------------------------------
extern "C" void kernel_launch(void* const* d_in, const int* in_sizes, int n_in,
                              void* d_out, int out_size, void* d_ws, size_t ws_size,
                              hipStream_t stream) {
  const float* x  = (const float*)d_in[0];
  const float* qw = (const float*)d_in[1];
  const float* qb = (const float*)d_in[2];
  const float* kw = (const float*)d_in[3];
  const float* kb = (const float*)d_in[4];
  const float* vw = (const float*)d_in[5];
  const float* vb = (const float*)d_in[6];
  const float* w1 = (const float*)d_in[7];
  const float* b1 = (const float*)d_in[8];
  const float* w2 = (const float*)d_in[9];
  const float* b2 = (const float*)d_in[10];
  float* out = (float*)d_out;   // [hidden(8388608) | k(2097152) | v(8388608)]
  char* ws = (char*)d_ws;

  const size_t MB = 1048576;
  unsigned short* Xb    = (unsigned short*)(ws + 0 * MB);    // 16M, dead after QKV
  unsigned short* QKVWb = (unsigned short*)(ws + 16 * MB);   // 12M, dead after QKV
  unsigned short* Pb    = (unsigned short*)(ws + 0 * MB);    // 32M, overlays Xb+QKVWb
  unsigned short* W1b   = (unsigned short*)(ws + 32 * MB);   //  8M
  unsigned short* W2b   = (unsigned short*)(ws + 40 * MB);   //  8M
  unsigned short* Qb    = (unsigned short*)(ws + 48 * MB);   //  4M
  unsigned short* Kb    = (unsigned short*)(ws + 52 * MB);   //  4M
  unsigned short* VTb   = (unsigned short*)(ws + 72 * MB);   // 16M (written by QKV)
  unsigned short* Scb   = (unsigned short*)(ws + 88 * MB);   // 32M bf16 scores, dead after softmax
  float*          XR    = (float*)(ws + 88 * MB);            // 32M overlays dead Scb
  unsigned short* X1b   = (unsigned short*)(ws + 120 * MB);  // 16M
  unsigned short* XRb   = (unsigned short*)(ws + 136 * MB);  // 16M

  // one fused cast: x->Xb, [qw;kw;vw]->QKVWb, w1->W1b, w2->W2b
  cast_all_kernel<<<22528, 256, 0, stream>>>(
      x, qw, kw, vw, w1, w2, Xb, QKVWb, W1b, W2b);

  // q,k,v = x @ [qw;kw;vw]^T + bias; V^T written directly (768 blocks, 3/CU)
  gemm_qkv_kernel<<<dim3(32, 24), dim3(256), 0, stream>>>(
      Xb, QKVWb, SEQ, 3072, DMODEL, qb, kb, vb,
      out + 8388608, out + 10485760, Qb, Kb, VTb);
  // scores = (q @ k^T) / sqrt(512)  -> bf16
  gemm256_kernel<<<dim3(16, 16), dim3(512), 0, stream>>>(
      Qb, Kb, SEQ, SEQ, DINT, nullptr, nullptr,
      0.04419417382415922f, 0, nullptr, Scb);
  // P = softmax(scores)  -> bf16
  softmax_kernel<<<4096, dim3(256), 0, stream>>>(Scb, Pb);
  // x_residual = P @ V + x  -> fp32 + bf16
  gemm256x128_k3_kernel<<<dim3(16, 16), dim3(512), 0, stream>>>(
      Pb, VTb, SEQ, DMODEL, SEQ, nullptr, x, 1.0f, 0, XR, XRb);
  // x1 = relu(x_residual @ w1^T + b1)  -> bf16
  gemm256x128_k3_kernel<<<dim3(16, 16), dim3(512), 0, stream>>>(
      XRb, W1b, SEQ, DMODEL, DMODEL, b1, nullptr, 1.0f, 1, nullptr, X1b);
  // hidden = x1 @ w2^T + b2 + x_residual  -> fp32 (out)
  gemm256x128_k3_kernel<<<dim3(16, 16), dim3(512), 0, stream>>>(
      X1b, W2b, SEQ, DMODEL, DMODEL, b2, XR, 1.0f, 0, out, nullptr);
}

// Round 14
// 315.209 us; speedup vs baseline: 1.7817x; 1.0325x over previous
//
#include <hip/hip_runtime.h>
#include <cstdint>
#include <cstddef>

// ---------------------------------------------------------------------------
// TransformerLayer: hidden,k,v = f(x, qw,qb, kw,kb, vw,vb, w1,b1, w2,b2)
// S=4096, D_MODEL=2048, D_INT=512.  bf16 MFMA GEMMs, fp32 accumulate.
// Round 14: (1) XR fp32 dropped -- P-V writes only XRb, FF2 residual reads
// bf16; (2) k32 test arm on FF1: 128^2/BK=32/3-buffer counted-vmcnt(4)/
// grid 512 = 2 blk/CU (occupancy x pipeline combo); P-V/FF2 on k3 control.
// ---------------------------------------------------------------------------

typedef __attribute__((ext_vector_type(8))) short short8;   // 8 x bf16 bits
typedef __attribute__((ext_vector_type(4))) float f32x4;    // MFMA accum

typedef __attribute__((address_space(3))) void lds_void;
typedef __attribute__((address_space(1))) void g_void;

#define SEQ    4096
#define DMODEL 2048
#define DINT   512

#define MEMF() asm volatile("" ::: "memory")
#define BARRIER() do { MEMF(); __builtin_amdgcn_s_barrier(); MEMF(); } while (0)
#define VMCNT12() asm volatile("s_waitcnt vmcnt(12)" ::: "memory")
#define VMCNT6() asm volatile("s_waitcnt vmcnt(6)" ::: "memory")
#define VMCNT4() asm volatile("s_waitcnt vmcnt(4)" ::: "memory")
#define VMCNT0() asm volatile("s_waitcnt vmcnt(0)" ::: "memory")
#define LGKM0()  asm volatile("s_waitcnt lgkmcnt(0)" ::: "memory")

// fp32 -> bf16 bits, round-to-nearest-even
__device__ __forceinline__ unsigned short f2bf(float f) {
  union { float f; unsigned int u; } a;
  a.f = f;
  unsigned int u = a.u;
  u += 0x7fffu + ((u >> 16) & 1u);
  return (unsigned short)(u >> 16);
}
__device__ __forceinline__ float bf2f(unsigned short u) {
  union { unsigned int i; float f; } a;
  a.i = ((unsigned int)u) << 16;
  return a.f;
}

// ---------------------------------------------------------------------------
// fused cast: all six fp32 tensors -> bf16 in one launch (region lookup).
// ---------------------------------------------------------------------------
__global__ __launch_bounds__(256) void cast_all_kernel(
    const float* __restrict__ x,  const float* __restrict__ qw,
    const float* __restrict__ kw, const float* __restrict__ vw,
    const float* __restrict__ w1, const float* __restrict__ w2,
    unsigned short* __restrict__ Xb, unsigned short* __restrict__ QKVWb,
    unsigned short* __restrict__ W1b, unsigned short* __restrict__ W2b) {
  const int i = blockIdx.x * 256 + threadIdx.x;
  const float* src; unsigned short* dst; int off;
  if (i < 2097152)      { src = x;  dst = Xb;               off = i; }
  else if (i < 2359296) { src = qw; dst = QKVWb;            off = i - 2097152; }
  else if (i < 2621440) { src = kw; dst = QKVWb + 1048576;  off = i - 2359296; }
  else if (i < 3670016) { src = vw; dst = QKVWb + 2097152;  off = i - 2621440; }
  else if (i < 4718592) { src = w1; dst = W1b;              off = i - 3670016; }
  else                  { src = w2; dst = W2b;              off = i - 4718592; }
  float4 v = ((const float4*)src)[off];
  ushort4 o;
  o.x = f2bf(v.x); o.y = f2bf(v.y); o.z = f2bf(v.z); o.w = f2bf(v.w);
  ((ushort4*)dst)[off] = o;
}

// ---------------------------------------------------------------------------
// Fused QKV GEMM: 2-phase 128^2, BK=32 double-buffered (32 KiB LDS,
// grid (32,24)=768 -> 3 blk/CU).  V^T written directly.
// ---------------------------------------------------------------------------
__global__ __launch_bounds__(256)
void gemm_qkv_kernel(const unsigned short* __restrict__ A,
                     const unsigned short* __restrict__ W,
                     int M, int N, int K,
                     const float* __restrict__ qb,
                     const float* __restrict__ kb,
                     const float* __restrict__ vb,
                     float* __restrict__ outK,
                     float* __restrict__ outV,
                     unsigned short* __restrict__ Qb,
                     unsigned short* __restrict__ Kb,
                     unsigned short* __restrict__ VTb)
{
  __shared__ __align__(16) unsigned short As[2][128][32];
  __shared__ __align__(16) unsigned short Bs[2][128][32];

  const int tid  = threadIdx.x;
  const int lane = tid & 63;
  const int wave = tid >> 6;
  const int wr   = wave >> 1;
  const int wc   = wave & 1;
  const int brow = blockIdx.x * 128;
  const int bcol = blockIdx.y * 128;
  const int lr   = lane & 15;
  const int kg   = lane >> 4;

  const int srow  = tid >> 2;          // 0..63
  const int scol  = (tid & 3) * 8;
  const int wbase = wave * 16;
  const unsigned short* Ab = A + (size_t)(brow + srow) * K + scol;
  const unsigned short* Bb = W + (size_t)(bcol + srow) * K + scol;

  f32x4 acc[4][4];
#pragma unroll
  for (int i = 0; i < 4; i++)
#pragma unroll
    for (int j = 0; j < 4; j++) acc[i][j] = (f32x4){0.f, 0.f, 0.f, 0.f};

  auto stage = [&](int d, int k0) {
#pragma unroll
    for (int j = 0; j < 2; ++j) {
      __builtin_amdgcn_global_load_lds((const g_void*)(Ab + (size_t)(j * 64) * K + k0),
                                       (lds_void*)&As[d][j * 64 + wbase][0], 16, 0, 0);
      __builtin_amdgcn_global_load_lds((const g_void*)(Bb + (size_t)(j * 64) * K + k0),
                                       (lds_void*)&Bs[d][j * 64 + wbase][0], 16, 0, 0);
    }
  };

  auto compute = [&](int d) {
    short8 aF[4], bF[4];
#pragma unroll
    for (int mi = 0; mi < 4; ++mi)
      aF[mi] = *(const short8*)&As[d][wr * 64 + mi * 16 + lr][kg * 8];
#pragma unroll
    for (int ni = 0; ni < 4; ++ni)
      bF[ni] = *(const short8*)&Bs[d][wc * 64 + ni * 16 + lr][kg * 8];
#pragma unroll
    for (int mi = 0; mi < 4; ++mi)
#pragma unroll
      for (int ni = 0; ni < 4; ++ni)
        acc[mi][ni] = __builtin_amdgcn_mfma_f32_16x16x32_bf16(
            aF[mi], bF[ni], acc[mi][ni], 0, 0, 0);
  };

  stage(0, 0);
  __syncthreads();
  int c = 0;
  const int NT = K >> 5;
  for (int t = 0; t < NT; ++t) {
    if (t + 1 < NT) stage(c ^ 1, (t + 1) << 5);
    compute(c);
    __syncthreads();
    c ^= 1;
  }

#pragma unroll
  for (int mi = 0; mi < 4; mi++) {
#pragma unroll
    for (int ni = 0; ni < 4; ni++) {
      const int row0 = brow + wr * 64 + mi * 16 + kg * 4;
      const int col  = bcol + wc * 64 + ni * 16 + lr;
      if (col < 512) {                       // q -> Qb bf16
        const float b = qb[col];
#pragma unroll
        for (int r = 0; r < 4; r++)
          Qb[(size_t)(row0 + r) * 512 + col] = f2bf(acc[mi][ni][r] + b);
      } else if (col < 1024) {               // k -> outK fp32 + Kb bf16
        const int c2 = col - 512;
        const float b = kb[c2];
#pragma unroll
        for (int r = 0; r < 4; r++) {
          const float t = acc[mi][ni][r] + b;
          outK[(size_t)(row0 + r) * 512 + c2] = t;
          Kb[(size_t)(row0 + r) * 512 + c2] = f2bf(t);
        }
      } else {                               // v -> outV fp32 + VTb (transposed)
        const int c2 = col - 1024;
        const float b = vb[c2];
        ushort4 o;
#pragma unroll
        for (int r = 0; r < 4; r++) {
          const float t = acc[mi][ni][r] + b;
          outV[(size_t)(row0 + r) * 2048 + c2] = t;
          ((unsigned short*)&o)[r] = f2bf(t);
        }
        *(ushort4*)(&VTb[(size_t)c2 * 4096 + row0]) = o;
      }
    }
  }
}

// ---------------------------------------------------------------------------
// 256^2 4-phase GEMM (scores GEMM, 2-D grid (16,16)).
// ---------------------------------------------------------------------------
__global__ __launch_bounds__(512, 2)
void gemm256_kernel(const unsigned short* __restrict__ A,
                    const unsigned short* __restrict__ B,
                    int M, int N, int K,
                    float scale, unsigned short* __restrict__ outB)
{
  __shared__ __align__(16) unsigned short lds[2][2][2][128][64];  // 128 KiB

  const int tid  = threadIdx.x;
  const int lane = tid & 63;
  const int wave = tid >> 6;
  const int wm   = wave >> 2;
  const int wn   = wave & 3;
  const int lr   = lane & 15;
  const int kg   = lane >> 4;
  const int brow = blockIdx.x * 256;
  const int bcol = blockIdx.y * 256;

  const int srow = tid >> 3;
  const int ssw  = ((tid & 7) * 8) ^ ((srow & 7) << 3);
  const unsigned short* Asrc = A + (size_t)(brow + srow) * K + ssw;
  const unsigned short* Bsrc = B + (size_t)(bcol + srow) * K + ssw;

  char* lbase = (char*)&lds[0][0][0][0][0];
  const int woff = wave * 1024;

  f32x4 acc[8][4];
#pragma unroll
  for (int i = 0; i < 8; ++i)
#pragma unroll
    for (int j = 0; j < 4; ++j) acc[i][j] = (f32x4){0.f, 0.f, 0.f, 0.f};

  const int NT = K >> 6;

  auto SA = [&](int d, int h, int q, int tl) {
    __builtin_amdgcn_global_load_lds(
        (const g_void*)(Asrc + (size_t)(h * 128 + q * 64) * K + tl * 64),
        (lds_void*)(lbase + d * 32768 + h * 16384 + q * 8192 + woff), 16, 0, 0);
  };
  auto SB = [&](int d, int h, int q, int tl) {
    __builtin_amdgcn_global_load_lds(
        (const g_void*)(Bsrc + (size_t)(h * 128 + q * 64) * K + tl * 64),
        (lds_void*)(lbase + 65536 + d * 32768 + h * 16384 + q * 8192 + woff), 16, 0, 0);
  };

  auto LDA = [&](short8* a, int d, int mh, int ks) {
    const char* reg = lbase + d * 32768 + wm * 16384;
    const int ke = (ks * 32 + kg * 8) ^ ((lr & 7) << 3);
#pragma unroll
    for (int i = 0; i < 4; ++i) {
      const int row = (mh * 4 + i) * 16 + lr;
      a[i] = *(const short8*)(reg + row * 128 + ke * 2);
    }
  };
  auto LDB = [&](short8* b, int d, int ks) {
    const char* reg = lbase + 65536 + d * 32768 + (wn >> 1) * 16384;
    const int ke = (ks * 32 + kg * 8) ^ ((lr & 7) << 3);
#pragma unroll
    for (int n = 0; n < 4; ++n) {
      const int row = (wn & 1) * 64 + n * 16 + lr;
      b[n] = *(const short8*)(reg + row * 128 + ke * 2);
    }
  };

  auto MM = [&](int mh, short8* a, short8* b) {
    __builtin_amdgcn_s_setprio(1);
#pragma unroll
    for (int i = 0; i < 4; ++i)
#pragma unroll
      for (int n = 0; n < 4; ++n)
        acc[mh * 4 + i][n] = __builtin_amdgcn_mfma_f32_16x16x32_bf16(
            a[i], b[n], acc[mh * 4 + i][n], 0, 0, 0);
    __builtin_amdgcn_s_setprio(0);
  };

  SA(0, 0, 0, 0); SA(0, 0, 1, 0); SA(0, 1, 0, 0); SA(0, 1, 1, 0);
  SB(0, 0, 0, 0); SB(0, 0, 1, 0); SB(0, 1, 0, 0); SB(0, 1, 1, 0);
  SB(1, 0, 0, 1); SB(1, 0, 1, 1); SA(1, 0, 0, 1);
  SB(1, 1, 0, 1); SB(1, 1, 1, 1); SA(1, 1, 0, 1);
  VMCNT6();
  BARRIER();

  short8 aT[4], bF0[4], bF1[4];
  for (int t = 0; t < NT; ++t) {
    const int buf = t & 1, nb = buf ^ 1;
    const int t1 = (t + 1 < NT) ? t + 1 : NT - 1;
    const int t2 = (t + 2 < NT) ? t + 2 : NT - 1;

    LDA(aT, buf, 0, 0); LDB(bF0, buf, 0);
    SA(nb, 0, 1, t1); SA(nb, 1, 1, t1);
    BARRIER(); MM(0, aT, bF0); BARRIER();

    LDA(aT, buf, 0, 1); LDB(bF1, buf, 1);
    BARRIER(); MM(0, aT, bF1); BARRIER();

    LDA(aT, buf, 1, 0);
    SB(buf, 0, 0, t2); SB(buf, 0, 1, t2); SA(buf, 0, 0, t2);
    BARRIER(); MM(1, aT, bF0); BARRIER();

    LDA(aT, buf, 1, 1);
    SB(buf, 1, 0, t2); SB(buf, 1, 1, t2); SA(buf, 1, 0, t2);
    BARRIER(); MM(1, aT, bF1);
    VMCNT6();
    BARRIER();
  }
  VMCNT0();

#pragma unroll
  for (int mi = 0; mi < 8; ++mi) {
#pragma unroll
    for (int ni = 0; ni < 4; ++ni) {
#pragma unroll
      for (int r = 0; r < 4; ++r) {
        const int row = brow + wm * 128 + mi * 16 + kg * 4 + r;
        const int col = bcol + wn * 64 + ni * 16 + lr;
        outB[(size_t)row * N + col] = f2bf(acc[mi][ni][r] * scale);
      }
    }
  }
}

// ---------------------------------------------------------------------------
// 256x128 3-buffer counted-vmcnt GEMM (P-V, FF2 control).  144 KiB LDS.
// residB: optional bf16 residual (row-major [M,N]).
// ---------------------------------------------------------------------------
__global__ __launch_bounds__(512, 2)
void gemm256x128_k3_kernel(const unsigned short* __restrict__ A,
                           const unsigned short* __restrict__ B,
                           int M, int N, int K,
                           const float* __restrict__ bias,
                           const float* __restrict__ resid,
                           const unsigned short* __restrict__ residB,
                           float scale, int relu,
                           float* __restrict__ outF,
                           unsigned short* __restrict__ outB)
{
  __shared__ __align__(16) unsigned short lds[73728];   // 144 KiB

  const int tid  = threadIdx.x;
  const int lane = tid & 63;
  const int wave = tid >> 6;
  const int wm   = wave >> 1;
  const int wn   = wave & 1;
  const int lr   = lane & 15;
  const int kg   = lane >> 4;
  const int brow = blockIdx.x * 256;
  const int bcol = blockIdx.y * 128;

  const int srow = tid >> 3;
  const int ssw  = ((tid & 7) * 8) ^ ((srow & 7) << 3);
  const unsigned short* Asrc = A + (size_t)(brow + srow) * K + ssw;
  const unsigned short* Bsrc = B + (size_t)(bcol + srow) * K + ssw;

  char* lbase = (char*)&lds[0];
  const int woff = wave * 1024;

  f32x4 acc[4][4];
#pragma unroll
  for (int i = 0; i < 4; ++i)
#pragma unroll
    for (int j = 0; j < 4; ++j) acc[i][j] = (f32x4){0.f, 0.f, 0.f, 0.f};

  const int NT = K >> 6;

  auto STAGE = [&](int d, int tl) {
#pragma unroll
    for (int r = 0; r < 4; ++r)
      __builtin_amdgcn_global_load_lds(
          (const g_void*)(Asrc + (size_t)(r * 64) * K + tl * 64),
          (lds_void*)(lbase + d * 32768 + r * 8192 + woff), 16, 0, 0);
#pragma unroll
    for (int r = 0; r < 2; ++r)
      __builtin_amdgcn_global_load_lds(
          (const g_void*)(Bsrc + (size_t)(r * 64) * K + tl * 64),
          (lds_void*)(lbase + 98304 + d * 16384 + r * 8192 + woff), 16, 0, 0);
  };

  auto RD = [&](short8* a, short8* b, int d) {
#pragma unroll
    for (int ks = 0; ks < 2; ++ks) {
      const int ke = (ks * 32 + kg * 8) ^ ((lr & 7) << 3);
      const char* ra = lbase + d * 32768;
      const char* rb = lbase + 98304 + d * 16384;
#pragma unroll
      for (int mi = 0; mi < 4; ++mi)
        a[ks * 4 + mi] = *(const short8*)(ra + (wm * 64 + mi * 16 + lr) * 128 + ke * 2);
#pragma unroll
      for (int n = 0; n < 4; ++n)
        b[ks * 4 + n] = *(const short8*)(rb + (wn * 64 + n * 16 + lr) * 128 + ke * 2);
    }
  };

  auto MMALL = [&](short8* a, short8* b) {
    __builtin_amdgcn_s_setprio(1);
#pragma unroll
    for (int ks = 0; ks < 2; ++ks)
#pragma unroll
      for (int mi = 0; mi < 4; ++mi)
#pragma unroll
        for (int n = 0; n < 4; ++n)
          acc[mi][n] = __builtin_amdgcn_mfma_f32_16x16x32_bf16(
              a[ks * 4 + mi], b[ks * 4 + n], acc[mi][n], 0, 0, 0);
    __builtin_amdgcn_s_setprio(0);
  };

  STAGE(0, 0);
  STAGE(1, 1);
  STAGE(2, 2);
  VMCNT12();
  BARRIER();
  short8 aE[8], bE[8], aO[8], bO[8];
  RD(aE, bE, 0);
  LGKM0();

  for (int t = 0; t < NT; t += 2) {
    VMCNT6();
    BARRIER();
    STAGE(t % 3, (t + 3 < NT) ? t + 3 : NT - 1);
    RD(aO, bO, (t + 1) % 3);
    MMALL(aE, bE);
    LGKM0();
    VMCNT6();
    BARRIER();
    STAGE((t + 1) % 3, (t + 4 < NT) ? t + 4 : NT - 1);
    RD(aE, bE, (t + 2) % 3);
    MMALL(aO, bO);
    LGKM0();
  }
  VMCNT0();

#pragma unroll
  for (int mi = 0; mi < 4; ++mi) {
#pragma unroll
    for (int ni = 0; ni < 4; ++ni) {
#pragma unroll
      for (int r = 0; r < 4; ++r) {
        const int row = brow + wm * 64 + mi * 16 + kg * 4 + r;
        const int col = bcol + wn * 64 + ni * 16 + lr;
        float v = acc[mi][ni][r] * scale;
        if (bias)   v += bias[col];
        if (resid)  v += resid[(size_t)row * N + col];
        if (residB) v += bf2f(residB[(size_t)row * N + col]);
        if (relu)   v = fmaxf(v, 0.0f);
        if (outF)   outF[(size_t)row * N + col] = v;
        if (outB)   outB[(size_t)row * N + col] = f2bf(v);
      }
    }
  }
}

// ---------------------------------------------------------------------------
// k32 test arm (FF1): 128^2 tile, BK=32, 256 thr (4 waves, 64x64/wave),
// 3-buffer counted-vmcnt, 2-ahead staging, grid (32,16)=512 -> 2 blk/CU.
// LDS 48 KiB: A[3][128][32] + B[3][128][32].
// Per sub-iter: VMCNT4 (in flight {t:4,t+1:4}; drain oldest 4 = t) ->
// BARRIER -> STAGE(t+2 -> buf (t+2)%3) -> RD(t) -> MM(t) -> LGKM0.
// Swizzle: 4-slot rotation (col8 ^ (row&3)) on both stage-src and read.
// ---------------------------------------------------------------------------
__global__ __launch_bounds__(256, 2)
void gemm_k32_kernel(const unsigned short* __restrict__ A,
                     const unsigned short* __restrict__ B,
                     int M, int N, int K,
                     const float* __restrict__ bias, int relu,
                     unsigned short* __restrict__ outB)
{
  __shared__ __align__(16) unsigned short lds[24576];   // 48 KiB

  const int tid  = threadIdx.x;
  const int lane = tid & 63;
  const int wave = tid >> 6;     // 0..3
  const int wr   = wave >> 1;    // 0..1
  const int wc   = wave & 1;     // 0..1
  const int lr   = lane & 15;
  const int kg   = lane >> 4;
  const int brow = blockIdx.x * 128;
  const int bcol = blockIdx.y * 128;

  const int srow = tid >> 2;                              // 0..63
  const int ssw  = ((tid & 3) * 8) ^ ((srow & 3) << 3);   // pre-swizzled col
  const unsigned short* Asrc = A + (size_t)(brow + srow) * K + ssw;
  const unsigned short* Bsrc = B + (size_t)(bcol + srow) * K + ssw;

  char* lbase = (char*)&lds[0];
  const int woff = wave * 1024;

  f32x4 acc[4][4];
#pragma unroll
  for (int i = 0; i < 4; ++i)
#pragma unroll
    for (int j = 0; j < 4; ++j) acc[i][j] = (f32x4){0.f, 0.f, 0.f, 0.f};

  const int NT = K >> 5;   // 64 for K=2048

  // 4 glds: A rows 0-63,64-127 ; B rows 0-63,64-127  (each = 256thr x 16B)
  auto STAGE = [&](int d, int tl) {
#pragma unroll
    for (int r = 0; r < 2; ++r)
      __builtin_amdgcn_global_load_lds(
          (const g_void*)(Asrc + (size_t)(r * 64) * K + tl * 32),
          (lds_void*)(lbase + d * 8192 + r * 4096 + woff), 16, 0, 0);
#pragma unroll
    for (int r = 0; r < 2; ++r)
      __builtin_amdgcn_global_load_lds(
          (const g_void*)(Bsrc + (size_t)(r * 64) * K + tl * 32),
          (lds_void*)(lbase + 24576 + d * 8192 + r * 4096 + woff), 16, 0, 0);
  };

  auto RD = [&](short8* a, short8* b, int d) {
#pragma unroll
    for (int mi = 0; mi < 4; ++mi) {
      const int row = wr * 64 + mi * 16 + lr;
      a[mi] = *(const short8*)(lbase + d * 8192 + row * 64 + ((kg ^ (row & 3)) << 4));
    }
#pragma unroll
    for (int n = 0; n < 4; ++n) {
      const int row = wc * 64 + n * 16 + lr;
      b[n] = *(const short8*)(lbase + 24576 + d * 8192 + row * 64 + ((kg ^ (row & 3)) << 4));
    }
  };

  auto MM = [&](short8* a, short8* b) {
    __builtin_amdgcn_s_setprio(1);
#pragma unroll
    for (int mi = 0; mi < 4; ++mi)
#pragma unroll
      for (int n = 0; n < 4; ++n)
        acc[mi][n] = __builtin_amdgcn_mfma_f32_16x16x32_bf16(
            a[mi], b[n], acc[mi][n], 0, 0, 0);
    __builtin_amdgcn_s_setprio(0);
  };

  // prologue: tiles 0,1 -> bufs 0,1 (8 loads); drain tile 0 (4 stay in flight)
  STAGE(0, 0);
  STAGE(1, 1);
  VMCNT4();
  BARRIER();

  short8 aF[4], bF[4];
  int cur = 0, stg = 2;
  for (int t = 0; t < NT; ++t) {
    VMCNT4();                 // {t:4, t+1:4} outstanding; drain oldest 4 = t
    BARRIER();                // all waves' tile-t loads landed; t-1 reads done
    STAGE(stg, (t + 2 < NT) ? t + 2 : NT - 1);
    RD(aF, bF, cur);
    MM(aF, bF);
    LGKM0();
    cur = (cur == 2) ? 0 : cur + 1;
    stg = (stg == 2) ? 0 : stg + 1;
  }
  VMCNT0();

#pragma unroll
  for (int mi = 0; mi < 4; ++mi) {
#pragma unroll
    for (int ni = 0; ni < 4; ++ni) {
#pragma unroll
      for (int r = 0; r < 4; ++r) {
        const int row = brow + wr * 64 + mi * 16 + kg * 4 + r;
        const int col = bcol + wc * 64 + ni * 16 + lr;
        float v = acc[mi][ni][r];
        if (bias) v += bias[col];
        if (relu) v = fmaxf(v, 0.0f);
        outB[(size_t)row * N + col] = f2bf(v);
      }
    }
  }
}

// ---------------------------------------------------------------------------
// register-resident row softmax over bf16 scores.
// ---------------------------------------------------------------------------
__global__ __launch_bounds__(256) void softmax_kernel(
    const unsigned short* __restrict__ Scb, unsigned short* __restrict__ P) {
  __shared__ float redm[4];
  __shared__ float reds[4];
  const int tid = threadIdx.x;
  const int row = blockIdx.x;
  const unsigned short* src = Scb + (size_t)row * SEQ;

  short8 h0 = *(const short8*)(src + tid * 8);
  short8 h1 = *(const short8*)(src + tid * 8 + 2048);
  float f[16];
#pragma unroll
  for (int i = 0; i < 8; ++i) f[i]     = bf2f((unsigned short)h0[i]);
#pragma unroll
  for (int i = 0; i < 8; ++i) f[8 + i] = bf2f((unsigned short)h1[i]);

  float lmax = f[0];
#pragma unroll
  for (int i = 1; i < 16; ++i) lmax = fmaxf(lmax, f[i]);
#pragma unroll
  for (int off = 32; off > 0; off >>= 1)
    lmax = fmaxf(lmax, __shfl_xor(lmax, off, 64));
  if ((tid & 63) == 0) redm[tid >> 6] = lmax;
  __syncthreads();
  const float m = fmaxf(fmaxf(redm[0], redm[1]), fmaxf(redm[2], redm[3]));

  float lsum = 0.0f;
#pragma unroll
  for (int i = 0; i < 16; ++i) { f[i] = __expf(f[i] - m); lsum += f[i]; }
#pragma unroll
  for (int off = 32; off > 0; off >>= 1)
    lsum += __shfl_xor(lsum, off, 64);
  if ((tid & 63) == 0) reds[tid >> 6] = lsum;
  __syncthreads();
  const float inv = 1.0f / (reds[0] + reds[1] + reds[2] + reds[3]);

  unsigned short* dst = P + (size_t)row * SEQ;
  short8 o0, o1;
#pragma unroll
  for (int i = 0; i < 8; ++i) o0[i] = (short)f2bf(f[i] * inv);
#pragma unroll
  for (int i = 0; i < 8; ++i) o1[i] = (short)f2bf(f[8 + i] * inv);
  *(short8*)(dst + tid * 8)        = o0;
  *(short8*)(dst + tid * 8 + 2048) = o1;
}

// ---------------------------------------------------------------------------
// launch
// ---------------------------------------------------------------------------
extern "C" void kernel_launch(void* const* d_in, const int* in_sizes, int n_in,
                              void* d_out, int out_size, void* d_ws, size_t ws_size,
                              hipStream_t stream) {
  const float* x  = (const float*)d_in[0];
  const float* qw = (const float*)d_in[1];
  const float* qb = (const float*)d_in[2];
  const float* kw = (const float*)d_in[3];
  const float* kb = (const float*)d_in[4];
  const float* vw = (const float*)d_in[5];
  const float* vb = (const float*)d_in[6];
  const float* w1 = (const float*)d_in[7];
  const float* b1 = (const float*)d_in[8];
  const float* w2 = (const float*)d_in[9];
  const float* b2 = (const float*)d_in[10];
  float* out = (float*)d_out;   // [hidden(8388608) | k(2097152) | v(8388608)]
  char* ws = (char*)d_ws;

  const size_t MB = 1048576;
  unsigned short* Xb    = (unsigned short*)(ws + 0 * MB);    // 16M, dead after QKV
  unsigned short* QKVWb = (unsigned short*)(ws + 16 * MB);   // 12M, dead after QKV
  unsigned short* Pb    = (unsigned short*)(ws + 0 * MB);    // 32M, overlays Xb+QKVWb
  unsigned short* W1b   = (unsigned short*)(ws + 32 * MB);   //  8M
  unsigned short* W2b   = (unsigned short*)(ws + 40 * MB);   //  8M
  unsigned short* Qb    = (unsigned short*)(ws + 48 * MB);   //  4M
  unsigned short* Kb    = (unsigned short*)(ws + 52 * MB);   //  4M
  unsigned short* VTb   = (unsigned short*)(ws + 72 * MB);   // 16M (written by QKV)
  unsigned short* Scb   = (unsigned short*)(ws + 88 * MB);   // 32M, dead after softmax
  unsigned short* X1b   = (unsigned short*)(ws + 120 * MB);  // 16M
  unsigned short* XRb   = (unsigned short*)(ws + 136 * MB);  // 16M

  // one fused cast
  cast_all_kernel<<<22528, 256, 0, stream>>>(
      x, qw, kw, vw, w1, w2, Xb, QKVWb, W1b, W2b);

  // q,k,v = x @ [qw;kw;vw]^T + bias; V^T written directly (768 blocks, 3/CU)
  gemm_qkv_kernel<<<dim3(32, 24), dim3(256), 0, stream>>>(
      Xb, QKVWb, SEQ, 3072, DMODEL, qb, kb, vb,
      out + 8388608, out + 10485760, Qb, Kb, VTb);
  // scores = (q @ k^T) / sqrt(512)  -> bf16
  gemm256_kernel<<<dim3(16, 16), dim3(512), 0, stream>>>(
      Qb, Kb, SEQ, SEQ, DINT, 0.04419417382415922f, Scb);
  // P = softmax(scores)  -> bf16
  softmax_kernel<<<4096, dim3(256), 0, stream>>>(Scb, Pb);
  // x_residual = P @ V + x  -> bf16 only (XR fp32 dropped)
  gemm256x128_k3_kernel<<<dim3(16, 16), dim3(512), 0, stream>>>(
      Pb, VTb, SEQ, DMODEL, SEQ, nullptr, x, nullptr, 1.0f, 0, nullptr, XRb);
  // x1 = relu(x_residual @ w1^T + b1)  -> bf16   [k32 test arm, 512 blocks]
  gemm_k32_kernel<<<dim3(32, 16), dim3(256), 0, stream>>>(
      XRb, W1b, SEQ, DMODEL, DMODEL, b1, 1, X1b);
  // hidden = x1 @ w2^T + b2 + x_residual(bf16)  -> fp32 (out)  [k3 control]
  gemm256x128_k3_kernel<<<dim3(16, 16), dim3(512), 0, stream>>>(
      X1b, W2b, SEQ, DMODEL, DMODEL, b2, nullptr, XRb, 1.0f, 0, out, nullptr);
}